// Round 7
// baseline (619.745 us; speedup 1.0000x reference)
//
#include <hip/hip_runtime.h>
#include <math.h>

#define N_NODES 4096
#define WORDS   64
#define HID     256
#define VOCAB   50257
#define NCLASS  4
#define N_LEAF  2048
#define RNN_BLOCKS 256     // 1 block/CU -> all resident, spin-wait safe
#define POISON 0x7FFF7FFFu // half2 (NaN,NaN); finite packed rows never match

typedef _Float16 half2_t __attribute__((ext_vector_type(2)));

__device__ __forceinline__ float dot2f(half2_t a, half2_t b, float c) {
#if __has_builtin(__builtin_amdgcn_fdot2)
  return __builtin_amdgcn_fdot2(a, b, c, false);   // v_dot2_f32_f16
#else
  return c + (float)a.x * (float)b.x + (float)a.y * (float)b.y;
#endif
}

__device__ __forceinline__ half2_t f2h2(float f) {
  union { float f; half2_t h; } u; u.f = f; return u.h;
}

__device__ __forceinline__ float fast_rcp(float x) { return __builtin_amdgcn_rcpf(x); }
__device__ __forceinline__ float fast_sigmoid(float x) {        // rcp-based, no IEEE div seq
  return fast_rcp(1.f + __expf(-x));
}
__device__ __forceinline__ float fast_tanh(float x) {           // 1 - 2/(e^{2x}+1); saturates to +-1
  return 1.f - 2.f * fast_rcp(1.f + __expf(2.f * x));
}
__device__ __forceinline__ half2_t pkrtz(float a, float b) {    // single v_cvt_pkrtz_f16_f32
#if __has_builtin(__builtin_amdgcn_cvt_pkrtz)
  return __builtin_bit_cast(half2_t, __builtin_amdgcn_cvt_pkrtz(a, b));
#else
  half2_t v; v.x = (_Float16)a; v.y = (_Float16)b; return v;
#endif
}

// ---------------------------------------------------------------- poison Hpk (the handoff medium)
__global__ void poison_hpk_kernel(unsigned* __restrict__ HpkU) {
  int i = blockIdx.x * blockDim.x + threadIdx.x;
  if (i < N_NODES * (HID / 2)) HpkU[i] = POISON;
}

// ---------------------------------------------------------------- E (HID,VOCAB) f32 -> ETh (VOCAB,HID) f16
__global__ void transpose_f16_kernel(const float* __restrict__ src, _Float16* __restrict__ dst,
                                     int R, int C) {
  __shared__ float tile[32][33];
  int c0 = blockIdx.x * 32, r0 = blockIdx.y * 32;
  int tx = threadIdx.x, ty = threadIdx.y;
#pragma unroll
  for (int j = 0; j < 32; j += 8) {
    int c = c0 + tx, r = r0 + ty + j;
    if (c < C) tile[ty + j][tx] = src[(size_t)r * C + c];
  }
  __syncthreads();
#pragma unroll
  for (int j = 0; j < 32; j += 8) {
    int c = c0 + ty + j, r = r0 + tx;
    if (c < C) dst[(size_t)c * R + r] = (_Float16)tile[tx][ty + j];
  }
}

// ---------------------------------------------------------------- pack U and W -> half2
// Layout: packed[m][kp][h] = (M[h][2kp], M[h][2kp+1]), linear idx (m*4+s)*8192 + j*256 + h
// with kp = s*32+j. m = 0..5 -> Uz,Ur,Uh,Wz,Wr,Wh.
__global__ void __launch_bounds__(256) pack_u_kernel(
    const float* __restrict__ Uz, const float* __restrict__ Ur, const float* __restrict__ Uh,
    const float* __restrict__ Wz, const float* __restrict__ Wr, const float* __restrict__ Wh,
    half2_t* __restrict__ Upk) {
  __shared__ float tile[64][259];
  int m = blockIdx.x >> 2, g = blockIdx.x & 3;
  const float* U = m == 0 ? Uz : (m == 1 ? Ur : (m == 2 ? Uh : (m == 3 ? Wz : (m == 4 ? Wr : Wh))));
  int t = threadIdx.x;
  for (int r = 0; r < 64; ++r) tile[r][t] = U[(size_t)(g * 64 + r) * 256 + t];
  __syncthreads();
#pragma unroll
  for (int it = 0; it < 32; ++it) {
    int e = it * 256 + t;
    int hl = e & 63, kj = e >> 6, s = kj >> 5, j = kj & 31;
    half2_t v;
    v.x = (_Float16)tile[hl][s * 64 + 2 * j];
    v.y = (_Float16)tile[hl][s * 64 + 2 * j + 1];
    Upk[(size_t)(m * 4 + s) * 8192 + j * 256 + (g * 64 + hl)] = v;
  }
}

// ---------------------------------------------------------------- fused gather + 3-gate GEMV
// R15 (kept): one block per 4 nodes, 256 threads. Gather X rows -> f16 LDS, then
// A_m[i][n] = sum_kp dot2(Wpk[m][kp][n], Xh[i][kp]) with 4-node W reuse.
__global__ void __launch_bounds__(256) gather_gemv_kernel(
    const int* __restrict__ tree, const half2_t* __restrict__ ETh2,
    const half2_t* __restrict__ Upk,
    float* __restrict__ Az, float* __restrict__ Ar, float* __restrict__ Ah,
    float* __restrict__ H, half2_t* __restrict__ Hpk) {
  const int t  = threadIdx.x;
  const int i0 = blockIdx.x * 4;
  __shared__ int     vsf[4 * WORDS];       // 4 nodes' word ids (contiguous in tree)
  __shared__ float2  ps[256];              // gather partial sums
  __shared__ half2_t Xh[4][HID / 2];       // 4 nodes' X rows, f16 pairs

  vsf[t] = tree[(size_t)i0 * WORDS + t];   // 4*64 = 256 words, coalesced
  __syncthreads();

  const int c    = t & 127;                // half2 column
  const int half = t >> 7;                 // word-half
#pragma unroll
  for (int n = 0; n < 4; ++n) {
    float ax = 0.f, ay = 0.f;
    const int base = n * WORDS + half * 32;
#pragma unroll 8
    for (int w = 0; w < 32; ++w) {
      half2_t e = ETh2[(size_t)vsf[base + w] * (HID / 2) + c];
      ax += (float)e.x;
      ay += (float)e.y;
    }
    ps[t].x = ax; ps[t].y = ay;
    __syncthreads();
    if (t < 128) {
      float xx = ps[t].x + ps[t + 128].x;
      float yy = ps[t].y + ps[t + 128].y;
      half2_t hv; hv.x = (_Float16)xx; hv.y = (_Float16)yy;   // RNE casts (match old gather)
      Xh[n][t] = hv;
      if (i0 + n == 0) {                   // node 0: seed fp32 H row + packed Hpk row
        float2 v2; v2.x = xx; v2.y = yy;
        ((float2*)H)[t] = v2;
        Hpk[t] = hv;
      }
    }
    __syncthreads();                       // ps reusable; Xh[n] visible to all
  }

  // ---- GEMV: 3 gates x 4 nodes, output neuron = t
  float acc[3][4];
#pragma unroll
  for (int m = 0; m < 3; ++m)
#pragma unroll
    for (int n = 0; n < 4; ++n) acc[m][n] = 0.f;

  const half2_t* wb = Upk + (size_t)12 * 8192 + t;   // m=3 (Wz) base, +32768 per gate
#pragma unroll 8
  for (int kp = 0; kp < 128; ++kp) {
    half2_t w0 = wb[kp * 256];
    half2_t w1 = wb[kp * 256 + 32768];
    half2_t w2 = wb[kp * 256 + 65536];
    half2_t x0 = Xh[0][kp], x1 = Xh[1][kp], x2 = Xh[2][kp], x3 = Xh[3][kp];  // LDS broadcast
    acc[0][0] = dot2f(w0, x0, acc[0][0]); acc[0][1] = dot2f(w0, x1, acc[0][1]);
    acc[0][2] = dot2f(w0, x2, acc[0][2]); acc[0][3] = dot2f(w0, x3, acc[0][3]);
    acc[1][0] = dot2f(w1, x0, acc[1][0]); acc[1][1] = dot2f(w1, x1, acc[1][1]);
    acc[1][2] = dot2f(w1, x2, acc[1][2]); acc[1][3] = dot2f(w1, x3, acc[1][3]);
    acc[2][0] = dot2f(w2, x0, acc[2][0]); acc[2][1] = dot2f(w2, x1, acc[2][1]);
    acc[2][2] = dot2f(w2, x2, acc[2][2]); acc[2][3] = dot2f(w2, x3, acc[2][3]);
  }
#pragma unroll
  for (int n = 0; n < 4; ++n) {
    Az[(size_t)(i0 + n) * HID + t] = acc[0][n];
    Ar[(size_t)(i0 + n) * HID + t] = acc[1][n];
    Ah[(size_t)(i0 + n) * HID + t] = acc[2][n];
  }
}

// ---------------------------------------------------------------- persistent wavefront GRU scan (paired block-cyclic)
// R17: R15's proven per-node compute (um/uhh split, B0/B1/B2) + NODE PAIRING.
// Evidence through R16: t_step is dominated by the global handoff (store -> L3 visibility ->
// poll detect -> row read, ~800-1100cy), not compute issue (R14/R16 rearranged compute, both
// lost) and not AGPR residency (R16: occupancy up, VGPR down, perf down).
// Pairing: block b owns nodes {2b, 2b+1} (stride 512). Static ownership -> no duplication
// (R2's flaw impossible). If parent(2b+1)==2b (checked from edge[] BEFORE polling -- also
// prevents self-poll deadlock), the epilogue of 2b writes the packed row into php1 via LDS
// and node 2b+1 skips the global poll entirely: half of all chain handoffs become ~free.
// Jump pairs poll BOTH parents concurrently (lanes 0-127 -> p0, 128-255 -> p1).
// Cost: 2b+1 is program-serialized behind 2b (+1 compute latency on paths through it) --
// cheap in the chain-dominated early region where the critical path lives.
// Race audit: php0 written pre-B0, read until B1. php1 written pre-B0 (pollers) XOR pre-B3
// (epilogue, fast1) -- fast1-exclusive; read post-B3/B0 until B1'; next poller write
// separated by B2'. rhp/part write->read pairs separated by B1/B2/B3/B1'/B2' as in R0.
// All barriers block-uniform (do0, fast1 derived from uniform edge[] data).
// Liveness: parents of pair (i0,i1) are < i0 (or == i0, handled in-block); induction
// grounds at node 0 (seeded by gather). Escape hatch 1<<22 -> diagnosable poison, no hang.
// All U loops FULLY unrolled (R6 lesson: partial unroll -> alloca -> LDS/scratch catastrophe).
__global__ void
__attribute__((amdgpu_flat_work_group_size(512, 512), amdgpu_waves_per_eu(2, 2)))
rnn_kernel(
    const float* __restrict__ Az, const float* __restrict__ Ar, const float* __restrict__ Ah,
    const half2_t* __restrict__ Upk,
    const float* __restrict__ bz, const float* __restrict__ br, const float* __restrict__ bh,
    const int* __restrict__ edge, float* __restrict__ H, unsigned* HpkU) {
  const int tid = threadIdx.x;
  const int h   = tid & (HID - 1);
  const int ks  = tid >> 8;            // 0..1
  __shared__ half2_t php0[HID / 2];
  __shared__ half2_t php1[HID / 2];
  __shared__ half2_t rhp[HID / 2];
  __shared__ float   part[2 * HID];

  // one-time U load (full unroll -> SSA -> register file)
  half2_t um[128];   // Uz (ks0) or Ur (ks1), full K
  half2_t uhh[64];   // Uh, k-slice [ks*128, ks*128+128)
  {
    const half2_t* mb = Upk + (size_t)(ks ? 4 : 0) * 8192 + h;
#pragma unroll
    for (int j = 0; j < 128; ++j)
      um[j] = mb[(j >> 5) * 8192 + (j & 31) * 256];
    const half2_t* hb = Upk + (size_t)(8 + 2 * ks) * 8192 + h;
#pragma unroll
    for (int j = 0; j < 64; ++j)
      uhh[j] = hb[(j >> 5) * 8192 + (j & 31) * 256];
  }
  const float b1  = ks ? br[h] : bz[h];
  const float bhv = ks ? 0.f : bh[h];

  for (int base = 2 * blockIdx.x; base < N_NODES; base += 2 * RNN_BLOCKS) {
    const int i0 = base, i1 = base + 1;
    const bool do0   = (i0 != 0);            // node 0 pre-seeded by gather
    const bool fast1 = do0 && (edge[2 * i1] == i0);   // intra-pair chain edge -> LDS handoff

    // A-row loads for BOTH nodes issued before the polls; they complete while waiting
    const float a1_0 = ks ? Ar[(size_t)i0 * HID + h] : Az[(size_t)i0 * HID + h];
    const float a2_0 = ks ? 0.f : Ah[(size_t)i0 * HID + h];
    const float a1_1 = ks ? Ar[(size_t)i1 * HID + h] : Az[(size_t)i1 * HID + h];
    const float a2_1 = ks ? 0.f : Ah[(size_t)i1 * HID + h];

    // concurrent polls: lanes 0-127 -> parent(i0), lanes 128-255 -> parent(i1)
    if (do0 && tid < HID / 2) {
      const int p0 = edge[2 * i0];           // parent, p0 < i0
      unsigned v = __hip_atomic_load(&HpkU[(size_t)p0 * (HID / 2) + tid],
                                     __ATOMIC_RELAXED, __HIP_MEMORY_SCOPE_AGENT);
      long spin = 0;
      while (v == POISON) {
        if (++spin > (1L << 22)) break;      // escape hatch (should never trigger)
        v = __hip_atomic_load(&HpkU[(size_t)p0 * (HID / 2) + tid],
                              __ATOMIC_RELAXED, __HIP_MEMORY_SCOPE_AGENT);
      }
      php0[tid] = __builtin_bit_cast(half2_t, v);
    }
    if (!fast1 && tid >= HID / 2 && tid < HID) {
      const int tl = tid - HID / 2;
      const int p1 = edge[2 * i1];           // parent, p1 < i1 (and != i0 unless !do0)
      unsigned v = __hip_atomic_load(&HpkU[(size_t)p1 * (HID / 2) + tl],
                                     __ATOMIC_RELAXED, __HIP_MEMORY_SCOPE_AGENT);
      long spin = 0;
      while (v == POISON) {
        if (++spin > (1L << 22)) break;      // escape hatch (should never trigger)
        v = __hip_atomic_load(&HpkU[(size_t)p1 * (HID / 2) + tl],
                              __ATOMIC_RELAXED, __HIP_MEMORY_SCOPE_AGENT);
      }
      php1[tl] = __builtin_bit_cast(half2_t, v);
    }
    __syncthreads();   // B0: php0 (and php1 unless fast1) resident in LDS

    if (do0) {
      // ================= node i0 (R15 compute verbatim, php0) =================
      half2_t ph2 = php0[h >> 1];
      const float phv = (float)((h & 1) ? ph2.y : ph2.x);

      float ac0 = a1_0 + b1, ac1 = 0.f, ac2 = 0.f, ac3 = 0.f;
      {
        const float4* phq = (const float4*)php0;
#pragma unroll
        for (int q = 0; q < 32; ++q) {
          float4 blk = phq[q];
          ac0 = dot2f(um[4 * q + 0], f2h2(blk.x), ac0);
          ac1 = dot2f(um[4 * q + 1], f2h2(blk.y), ac1);
          ac2 = dot2f(um[4 * q + 2], f2h2(blk.z), ac2);
          ac3 = dot2f(um[4 * q + 3], f2h2(blk.w), ac3);
        }
      }
      const float g = fast_sigmoid((ac0 + ac1) + (ac2 + ac3));
      if (ks) {                    // r gate -> packed r*ph
        float rh = g * phv;
        float nb = __shfl_xor(rh, 1, 64);
        if ((h & 1) == 0) rhp[h >> 1] = pkrtz(rh, nb);
      }
      __syncthreads();   // B1

      float c0 = 0.f, c1 = 0.f;
      {
        const float4* rq = (const float4*)(rhp + ks * 64);
#pragma unroll
        for (int q = 0; q < 16; ++q) {
          float4 blk = rq[q];
          c0 = dot2f(uhh[4 * q + 0], f2h2(blk.x), c0);
          c1 = dot2f(uhh[4 * q + 1], f2h2(blk.y), c1);
          c0 = dot2f(uhh[4 * q + 2], f2h2(blk.z), c0);
          c1 = dot2f(uhh[4 * q + 3], f2h2(blk.w), c1);
        }
      }
      part[ks * HID + h] = c0 + c1;
      __syncthreads();   // B2

      if (ks == 0) {
        float ca = a2_0 + bhv + part[h] + part[HID + h];
        float c  = fast_tanh(ca);
        float hn = fmaf(g, phv, (1.f - g) * c);
        float nb = __shfl_xor(hn, 1, 64);   // DPP xor-1
        if ((h & 1) == 0) {
          unsigned pk = __builtin_bit_cast(unsigned, pkrtz(hn, nb));
          __hip_atomic_store(&HpkU[(size_t)i0 * (HID / 2) + (h >> 1)], pk,
                             __ATOMIC_RELAXED, __HIP_MEMORY_SCOPE_AGENT);
          if (fast1) php1[h >> 1] = __builtin_bit_cast(half2_t, pk);  // LDS handoff to i1
        }
        H[(size_t)i0 * HID + h] = hn;       // fp32 row for leafmax (off critical path)
      }
      __syncthreads();   // B3: php1 handoff visible; part/rhp reusable
    }

    // ================= node i1 (R15 compute verbatim, php1) =================
    {
      half2_t ph2 = php1[h >> 1];
      const float phv = (float)((h & 1) ? ph2.y : ph2.x);

      float ac0 = a1_1 + b1, ac1 = 0.f, ac2 = 0.f, ac3 = 0.f;
      {
        const float4* phq = (const float4*)php1;
#pragma unroll
        for (int q = 0; q < 32; ++q) {
          float4 blk = phq[q];
          ac0 = dot2f(um[4 * q + 0], f2h2(blk.x), ac0);
          ac1 = dot2f(um[4 * q + 1], f2h2(blk.y), ac1);
          ac2 = dot2f(um[4 * q + 2], f2h2(blk.z), ac2);
          ac3 = dot2f(um[4 * q + 3], f2h2(blk.w), ac3);
        }
      }
      const float g = fast_sigmoid((ac0 + ac1) + (ac2 + ac3));
      if (ks) {                    // r gate -> packed r*ph
        float rh = g * phv;
        float nb = __shfl_xor(rh, 1, 64);
        if ((h & 1) == 0) rhp[h >> 1] = pkrtz(rh, nb);
      }
      __syncthreads();   // B1'

      float c0 = 0.f, c1 = 0.f;
      {
        const float4* rq = (const float4*)(rhp + ks * 64);
#pragma unroll
        for (int q = 0; q < 16; ++q) {
          float4 blk = rq[q];
          c0 = dot2f(uhh[4 * q + 0], f2h2(blk.x), c0);
          c1 = dot2f(uhh[4 * q + 1], f2h2(blk.y), c1);
          c0 = dot2f(uhh[4 * q + 2], f2h2(blk.z), c0);
          c1 = dot2f(uhh[4 * q + 3], f2h2(blk.w), c1);
        }
      }
      part[ks * HID + h] = c0 + c1;
      __syncthreads();   // B2'

      if (ks == 0) {
        float ca = a2_1 + bhv + part[h] + part[HID + h];
        float c  = fast_tanh(ca);
        float hn = fmaf(g, phv, (1.f - g) * c);
        float nb = __shfl_xor(hn, 1, 64);   // DPP xor-1
        if ((h & 1) == 0) {                 // handoff store FIRST (children poll this)
          __hip_atomic_store(&HpkU[(size_t)i1 * (HID / 2) + (h >> 1)],
                             __builtin_bit_cast(unsigned, pkrtz(hn, nb)),
                             __ATOMIC_RELAXED, __HIP_MEMORY_SCOPE_AGENT);
        }
        H[(size_t)i1 * HID + h] = hn;       // fp32 row for leafmax (off critical path)
      }
    }
    // loop -> next polls write php0/php1 pre-B0(next); all reads ended at B1'/B2'
  }
}

// ---------------------------------------------------------------- leaf max partial (64 blocks x 32 leaves)
__global__ void leafmax_kernel(const float* __restrict__ H, const int* __restrict__ leafs,
                               float* __restrict__ partial) {
  int b = blockIdx.x;
  int h = threadIdx.x;
  float m = -INFINITY;
#pragma unroll 4
  for (int j = 0; j < N_LEAF / 64; ++j) {
    int node = leafs[b * (N_LEAF / 64) + j];
    m = fmaxf(m, H[(size_t)node * HID + h]);
  }
  partial[b * HID + h] = m;
}

// ---------------------------------------------------------------- final: reduce partials, W_out, softmax, loss
__global__ void final_kernel(const float* __restrict__ partial, const float* __restrict__ W_out,
                             const float* __restrict__ b_out, const float* __restrict__ y,
                             float* __restrict__ out) {
  int h = threadIdx.x;
  float m = -INFINITY;
#pragma unroll 8
  for (int b = 0; b < 64; ++b) m = fmaxf(m, partial[b * HID + h]);
  __shared__ float fs[HID];
  __shared__ float red[HID];
  __shared__ float logit[NCLASS];
  fs[h] = m;
  __syncthreads();
  for (int c = 0; c < NCLASS; ++c) {
    red[h] = W_out[c * HID + h] * fs[h];
    __syncthreads();
    for (int s = HID / 2; s > 0; s >>= 1) {
      if (h < s) red[h] += red[h + s];
      __syncthreads();
    }
    if (h == 0) logit[c] = red[0] + b_out[c];
    __syncthreads();
  }
  if (h == 0) {
    float mx = logit[0];
    for (int c = 1; c < NCLASS; ++c) mx = fmaxf(mx, logit[c]);
    float e[NCLASS], s = 0.f;
    for (int c = 0; c < NCLASS; ++c) { e[c] = expf(logit[c] - mx); s += e[c]; }
    float loss = 0.f;
    for (int c = 0; c < NCLASS; ++c) {
      float p = e[c] / s;
      out[c] = p;
      float d = y[c] - p;
      loss += d * d;
    }
    out[NCLASS] = loss;
  }
}

// ---------------------------------------------------------------- launch
extern "C" void kernel_launch(void* const* d_in, const int* in_sizes, int n_in,
                              void* d_out, int out_size, void* d_ws, size_t ws_size,
                              hipStream_t stream) {
  const int*   tree = (const int*)d_in[0];
  const int*   edge = (const int*)d_in[1];
  const int*   leaf = (const int*)d_in[2];
  const float* y    = (const float*)d_in[3];
  const float* E    = (const float*)d_in[4];
  const float* Wz   = (const float*)d_in[5];
  const float* Uz   = (const float*)d_in[6];
  const float* bz   = (const float*)d_in[7];
  const float* Wr   = (const float*)d_in[8];
  const float* Ur   = (const float*)d_in[9];
  const float* br   = (const float*)d_in[10];
  const float* Wh   = (const float*)d_in[11];
  const float* Uh   = (const float*)d_in[12];
  const float* bh   = (const float*)d_in[13];
  const float* Wout = (const float*)d_in[14];
  const float* bout = (const float*)d_in[15];
  float* out = (float*)d_out;

  char* base = (char*)d_ws;
  size_t b = 0;
  _Float16* ETh = (_Float16*)(base + b); b += (size_t)VOCAB * HID * 2;      // 25.7 MB
  b = (b + 255) & ~(size_t)255;
  half2_t* Upk = (half2_t*)(base + b); b += (size_t)6 * 4 * 8192 * 4;       // U(3) + W(3) packed
  half2_t* Hpk = (half2_t*)(base + b); b += (size_t)N_NODES * (HID / 2) * 4;
  float* Az  = (float*)(base + b); b += (size_t)N_NODES * HID * 4;
  float* Ar  = (float*)(base + b); b += (size_t)N_NODES * HID * 4;
  float* Ah  = (float*)(base + b); b += (size_t)N_NODES * HID * 4;
  float* H   = (float*)(base + b); b += (size_t)N_NODES * HID * 4;
  float* partial = (float*)(base + b); b += (size_t)64 * HID * 4;

  poison_hpk_kernel<<<(N_NODES * (HID / 2) + 255) / 256, 256, 0, stream>>>((unsigned*)Hpk);
  transpose_f16_kernel<<<dim3((VOCAB + 31) / 32, HID / 32), dim3(32, 8), 0, stream>>>(E, ETh, HID, VOCAB);
  pack_u_kernel<<<24, 256, 0, stream>>>(Uz, Ur, Uh, Wz, Wr, Wh, Upk);
  gather_gemv_kernel<<<N_NODES / 4, 256, 0, stream>>>(tree, (const half2_t*)ETh, Upk,
                                                      Az, Ar, Ah, H, Hpk);
  rnn_kernel<<<RNN_BLOCKS, 512, 0, stream>>>(Az, Ar, Ah, Upk, bz, br, bh, edge, H, (unsigned*)Hpk);
  leafmax_kernel<<<64, HID, 0, stream>>>(H, leaf, partial);
  final_kernel<<<1, HID, 0, stream>>>(partial, Wout, bout, y, out);
}

// Round 8
// 562.798 us; speedup vs baseline: 1.1012x; 1.1012x over previous
//
#include <hip/hip_runtime.h>
#include <math.h>

#define N_NODES 4096
#define WORDS   64
#define HID     256
#define VOCAB   50257
#define NCLASS  4
#define N_LEAF  2048
#define RNN_BLOCKS 256     // 1 block/CU -> all resident, spin-wait safe
#define POISON 0x7FFF7FFFu // half2 (NaN,NaN); finite packed rows never match

typedef _Float16 half2_t __attribute__((ext_vector_type(2)));

__device__ __forceinline__ float dot2f(half2_t a, half2_t b, float c) {
#if __has_builtin(__builtin_amdgcn_fdot2)
  return __builtin_amdgcn_fdot2(a, b, c, false);   // v_dot2_f32_f16
#else
  return c + (float)a.x * (float)b.x + (float)a.y * (float)b.y;
#endif
}

__device__ __forceinline__ half2_t f2h2(float f) {
  union { float f; half2_t h; } u; u.f = f; return u.h;
}

__device__ __forceinline__ float fast_rcp(float x) { return __builtin_amdgcn_rcpf(x); }
__device__ __forceinline__ float fast_sigmoid(float x) {        // rcp-based, no IEEE div seq
  return fast_rcp(1.f + __expf(-x));
}
__device__ __forceinline__ float fast_tanh(float x) {           // 1 - 2/(e^{2x}+1); saturates to +-1
  return 1.f - 2.f * fast_rcp(1.f + __expf(2.f * x));
}
__device__ __forceinline__ half2_t pkrtz(float a, float b) {    // single v_cvt_pkrtz_f16_f32
#if __has_builtin(__builtin_amdgcn_cvt_pkrtz)
  return __builtin_bit_cast(half2_t, __builtin_amdgcn_cvt_pkrtz(a, b));
#else
  half2_t v; v.x = (_Float16)a; v.y = (_Float16)b; return v;
#endif
}

// ---------------------------------------------------------------- E (HID,VOCAB) f32 -> ETh (VOCAB,HID) f16
__global__ void transpose_f16_kernel(const float* __restrict__ src, _Float16* __restrict__ dst,
                                     int R, int C) {
  __shared__ float tile[32][33];
  int c0 = blockIdx.x * 32, r0 = blockIdx.y * 32;
  int tx = threadIdx.x, ty = threadIdx.y;
#pragma unroll
  for (int j = 0; j < 32; j += 8) {
    int c = c0 + tx, r = r0 + ty + j;
    if (c < C) tile[ty + j][tx] = src[(size_t)r * C + c];
  }
  __syncthreads();
#pragma unroll
  for (int j = 0; j < 32; j += 8) {
    int c = c0 + ty + j, r = r0 + tx;
    if (c < C) dst[(size_t)c * R + r] = (_Float16)tile[tx][ty + j];
  }
}

// ---------------------------------------------------------------- pack U and W -> half2 (+ poison role)
// Layout: packed[m][kp][h] = (M[h][2kp], M[h][2kp+1]), linear idx m*32768 + kp*256 + h.
// m = 0..5 -> Uz,Ur,Uh,Wz,Wr,Wh. Blocks >= 24 poison Hpk (merged launch, R18).
__global__ void __launch_bounds__(256) pack_u_kernel(
    const float* __restrict__ Uz, const float* __restrict__ Ur, const float* __restrict__ Uh,
    const float* __restrict__ Wz, const float* __restrict__ Wr, const float* __restrict__ Wh,
    half2_t* __restrict__ Upk, unsigned* __restrict__ HpkU) {
  if (blockIdx.x >= 24) {                    // poison role: 32 blocks x 16384 words
    int base = (blockIdx.x - 24) * 16384 + threadIdx.x;
#pragma unroll
    for (int k = 0; k < 64; ++k) HpkU[base + k * 256] = POISON;
    return;
  }
  __shared__ float tile[64][259];
  int m = blockIdx.x >> 2, g = blockIdx.x & 3;
  const float* U = m == 0 ? Uz : (m == 1 ? Ur : (m == 2 ? Uh : (m == 3 ? Wz : (m == 4 ? Wr : Wh))));
  int t = threadIdx.x;
  for (int r = 0; r < 64; ++r) tile[r][t] = U[(size_t)(g * 64 + r) * 256 + t];
  __syncthreads();
#pragma unroll
  for (int it = 0; it < 32; ++it) {
    int e = it * 256 + t;
    int hl = e & 63, kj = e >> 6, s = kj >> 5, j = kj & 31;
    half2_t v;
    v.x = (_Float16)tile[hl][s * 64 + 2 * j];
    v.y = (_Float16)tile[hl][s * 64 + 2 * j + 1];
    Upk[(size_t)(m * 4 + s) * 8192 + j * 256 + (g * 64 + hl)] = v;
  }
}

// ---------------------------------------------------------------- persistent wavefront GRU scan (block-cyclic)
// R18 = R15's PROVEN scan (byte-identical protocol: poll/B0/phase1/B1/phase2/B2/epilogue)
// + FUSED PROLOGUE: each block gathers X and computes the 3-gate GEMV for exactly the 16
// nodes it owns (i = b + 256r), holding A-rows in LDS. Kills the gather_gemv kernel, the
// 24MB A global round-trip, and 2 launch gaps. Block 0's prologue seeds node 0 (Hpk+H).
// Evidence basis (R14/R16/R17 post-mortems): t_step is dominated by the INVARIANT 768cy
// VALU floor + small overheads; detect latency is cheap; every scan redesign regressed ->
// the scan is untouched here, the prologue is purely additive (no cross-block deps; Hpk
// poisoned by the prior pack launch, so row-0 polls ground correctly).
// sched_barrier(0) pins the prologue/U-load boundary (keeps 192 U-loads from hoisting into
// the prologue -> register blowup). All register-array loops FULLY unrolled (R6 lesson).
__global__ void
__attribute__((amdgpu_flat_work_group_size(512, 512), amdgpu_waves_per_eu(2, 2)))
rnn_kernel(
    const int* __restrict__ tree, const half2_t* __restrict__ ETh2,
    const half2_t* __restrict__ Upk,
    const float* __restrict__ bz, const float* __restrict__ br, const float* __restrict__ bh,
    const int* __restrict__ edge, float* __restrict__ H, unsigned* HpkU) {
  const int tid = threadIdx.x;
  const int h   = tid & (HID - 1);
  const int ks  = tid >> 8;            // 0..1
  const int b   = blockIdx.x;
  __shared__ half2_t php[HID / 2];
  __shared__ half2_t rhp[HID / 2];
  __shared__ float   part[2 * HID];
  __shared__ int     vsAll[16][WORDS];          // 16 owned nodes' word ids       (4 KB)
  __shared__ float2  ps16[16][4][HID / 2];      // gather partials                (64 KB)
  __shared__ half2_t Xh[16][HID / 2];           // 16 X rows, f16 pairs           (8 KB)
  __shared__ float   ldsA[16][3][HID];          // A-rows: [round][z,r,h][neuron] (48 KB)

  // ================= prologue 1: load the 16 owned nodes' words =================
#pragma unroll
  for (int m2 = 0; m2 < 2; ++m2) {
    int idx = tid + m2 * 512;
    int n = idx >> 6, w = idx & 63;
    vsAll[n][w] = tree[(size_t)(b + (n << 8)) * WORDS + w];
  }
  __syncthreads();

  // ================= prologue 2: gather X (thread: col c, word-group g) =========
  {
    const int c = tid & 127;
    const int g = tid >> 7;
    float ax[16], ay[16];
#pragma unroll
    for (int n = 0; n < 16; ++n) { ax[n] = 0.f; ay[n] = 0.f; }
#pragma unroll
    for (int n = 0; n < 16; ++n) {
#pragma unroll
      for (int w = 0; w < 16; ++w) {
        half2_t e = ETh2[(size_t)vsAll[n][g * 16 + w] * (HID / 2) + c];
        ax[n] += (float)e.x;
        ay[n] += (float)e.y;
      }
    }
#pragma unroll
    for (int n = 0; n < 16; ++n) { ps16[n][g][c].x = ax[n]; ps16[n][g][c].y = ay[n]; }
  }
  __syncthreads();

  // ================= prologue 3: combine groups -> f16 X rows; seed node 0 ======
#pragma unroll
  for (int k = 0; k < 4; ++k) {
    int o = tid + k * 512;
    int n = o >> 7, c = o & 127;
    float xx = (ps16[n][0][c].x + ps16[n][1][c].x) + (ps16[n][2][c].x + ps16[n][3][c].x);
    float yy = (ps16[n][0][c].y + ps16[n][1][c].y) + (ps16[n][2][c].y + ps16[n][3][c].y);
    half2_t hv; hv.x = (_Float16)xx; hv.y = (_Float16)yy;   // RNE casts (match old gather)
    Xh[n][c] = hv;
    if (b == 0 && n == 0) {                    // node 0: seed fp32 H row + packed Hpk row
      float2 v2; v2.x = xx; v2.y = yy;
      ((float2*)H)[c] = v2;
      __hip_atomic_store(&HpkU[c], __builtin_bit_cast(unsigned, hv),
                         __ATOMIC_RELAXED, __HIP_MEMORY_SCOPE_AGENT);
    }
  }
  __syncthreads();

  // ================= prologue 4: 3-gate GEMV over kp half [ks*64, ks*64+64) =====
  {
    float az[16], ar[16], ah[16];
#pragma unroll
    for (int n = 0; n < 16; ++n) { az[n] = 0.f; ar[n] = 0.f; ah[n] = 0.f; }
    const half2_t* wb = Upk + (size_t)98304 + h;   // m=3 (Wz); +32768 per gate
    const int kp0 = ks * 64;
#pragma unroll 4
    for (int kp = kp0; kp < kp0 + 64; ++kp) {      // kp runtime-indexed: LDS only (safe)
      half2_t w0 = wb[kp * 256];
      half2_t w1 = wb[kp * 256 + 32768];
      half2_t w2 = wb[kp * 256 + 65536];
#pragma unroll
      for (int n = 0; n < 16; ++n) {
        half2_t x = Xh[n][kp];
        az[n] = dot2f(w0, x, az[n]);
        ar[n] = dot2f(w1, x, ar[n]);
        ah[n] = dot2f(w2, x, ah[n]);
      }
    }
    if (ks == 0) {
#pragma unroll
      for (int n = 0; n < 16; ++n) {
        ldsA[n][0][h] = az[n]; ldsA[n][1][h] = ar[n]; ldsA[n][2][h] = ah[n];
      }
    }
    __syncthreads();
    if (ks == 1) {                               // RMW by ks1 only: no race
#pragma unroll
      for (int n = 0; n < 16; ++n) {
        ldsA[n][0][h] += az[n]; ldsA[n][1][h] += ar[n]; ldsA[n][2][h] += ah[n];
      }
    }
    __syncthreads();
  }
#if __has_builtin(__builtin_amdgcn_sched_barrier)
  __builtin_amdgcn_sched_barrier(0);   // pin: U-loads must not hoist into the prologue
#endif

  // ================= one-time U load (full unroll -> SSA -> register file) ======
  half2_t um[128];   // Uz (ks0) or Ur (ks1), full K
  half2_t uhh[64];   // Uh, k-slice [ks*128, ks*128+128)
  {
    const half2_t* mb = Upk + (size_t)(ks ? 4 : 0) * 8192 + h;
#pragma unroll
    for (int j = 0; j < 128; ++j)
      um[j] = mb[(j >> 5) * 8192 + (j & 31) * 256];
    const half2_t* hb = Upk + (size_t)(8 + 2 * ks) * 8192 + h;
#pragma unroll
    for (int j = 0; j < 64; ++j)
      uhh[j] = hb[(j >> 5) * 8192 + (j & 31) * 256];
  }
  const float b1  = ks ? br[h] : bz[h];
  const float bhv = ks ? 0.f : bh[h];

  // ================= scan: R15 verbatim (A-rows from LDS, r = i>>8) =============
  const int istart = b == 0 ? RNN_BLOCKS : b;    // node 0 pre-seeded by prologue
  for (int i = istart; i < N_NODES; i += RNN_BLOCKS) {
    const int p = edge[2 * i];   // parent, p < i
    const int r = i >> 8;        // owned-round index (b < 256)
    const float a1 = ks ? ldsA[r][1][h] : ldsA[r][0][h];
    const float a2 = ks ? 0.f : ldsA[r][2][h];

    if (tid < HID / 2) {
      unsigned v = __hip_atomic_load(&HpkU[(size_t)p * (HID / 2) + tid],
                                     __ATOMIC_RELAXED, __HIP_MEMORY_SCOPE_AGENT);
      long spin = 0;
      while (v == POISON) {
        if (++spin > (1L << 22)) break;   // escape hatch (should never trigger)
        v = __hip_atomic_load(&HpkU[(size_t)p * (HID / 2) + tid],
                              __ATOMIC_RELAXED, __HIP_MEMORY_SCOPE_AGENT);
      }
      php[tid] = __builtin_bit_cast(half2_t, v);
    }
    __syncthreads();   // B0: packed parent row resident in LDS

    // parent element for this h, decoded from fp16 row
    half2_t ph2 = php[h >> 1];
    const float phv = (float)((h & 1) ? ph2.y : ph2.x);

    // phase 1: full-K dot of Uz (ks0) / Ur (ks1) against packed parent row
    float ac0 = a1 + b1, ac1 = 0.f, ac2 = 0.f, ac3 = 0.f;
    {
      const float4* phq = (const float4*)php;
#pragma unroll
      for (int q = 0; q < 32; ++q) {
        float4 blk = phq[q];
        ac0 = dot2f(um[4 * q + 0], f2h2(blk.x), ac0);
        ac1 = dot2f(um[4 * q + 1], f2h2(blk.y), ac1);
        ac2 = dot2f(um[4 * q + 2], f2h2(blk.z), ac2);
        ac3 = dot2f(um[4 * q + 3], f2h2(blk.w), ac3);
      }
    }
    const float g = fast_sigmoid((ac0 + ac1) + (ac2 + ac3));
    if (ks) {                    // r gate -> packed r*ph
      float rh = g * phv;
      float nb = __shfl_xor(rh, 1, 64);
      if ((h & 1) == 0) rhp[h >> 1] = pkrtz(rh, nb);
    }
    __syncthreads();   // B1

    // phase 2: Uh partial dots over this thread's k-slice
    float c0 = 0.f, c1 = 0.f;
    {
      const float4* rq = (const float4*)(rhp + ks * 64);
#pragma unroll
      for (int q = 0; q < 16; ++q) {
        float4 blk = rq[q];
        c0 = dot2f(uhh[4 * q + 0], f2h2(blk.x), c0);
        c1 = dot2f(uhh[4 * q + 1], f2h2(blk.y), c1);
        c0 = dot2f(uhh[4 * q + 2], f2h2(blk.z), c0);
        c1 = dot2f(uhh[4 * q + 3], f2h2(blk.w), c1);
      }
    }
    part[ks * HID + h] = c0 + c1;
    __syncthreads();   // B2

    if (ks == 0) {
      float ca = a2 + bhv + part[h] + part[HID + h];
      float c  = fast_tanh(ca);
      float hn = fmaf(g, phv, (1.f - g) * c);
      float nb = __shfl_xor(hn, 1, 64);   // DPP xor-1
      if ((h & 1) == 0) {                 // handoff store FIRST (children poll this)
        __hip_atomic_store(&HpkU[(size_t)i * (HID / 2) + (h >> 1)],
                           __builtin_bit_cast(unsigned, pkrtz(hn, nb)),
                           __ATOMIC_RELAXED, __HIP_MEMORY_SCOPE_AGENT);
      }
      H[(size_t)i * HID + h] = hn;        // fp32 row for leafmax (off critical path)
    }
    // no publish barrier, no waitcnt, no flag: the row stores are the signal
  }
}

// ---------------------------------------------------------------- leaf max partial (64 blocks x 32 leaves)
__global__ void leafmax_kernel(const float* __restrict__ H, const int* __restrict__ leafs,
                               float* __restrict__ partial) {
  int b = blockIdx.x;
  int h = threadIdx.x;
  float m = -INFINITY;
#pragma unroll 4
  for (int j = 0; j < N_LEAF / 64; ++j) {
    int node = leafs[b * (N_LEAF / 64) + j];
    m = fmaxf(m, H[(size_t)node * HID + h]);
  }
  partial[b * HID + h] = m;
}

// ---------------------------------------------------------------- final: reduce partials, W_out, softmax, loss
__global__ void final_kernel(const float* __restrict__ partial, const float* __restrict__ W_out,
                             const float* __restrict__ b_out, const float* __restrict__ y,
                             float* __restrict__ out) {
  int h = threadIdx.x;
  float m = -INFINITY;
#pragma unroll 8
  for (int b = 0; b < 64; ++b) m = fmaxf(m, partial[b * HID + h]);
  __shared__ float fs[HID];
  __shared__ float red[HID];
  __shared__ float logit[NCLASS];
  fs[h] = m;
  __syncthreads();
  for (int c = 0; c < NCLASS; ++c) {
    red[h] = W_out[c * HID + h] * fs[h];
    __syncthreads();
    for (int s = HID / 2; s > 0; s >>= 1) {
      if (h < s) red[h] += red[h + s];
      __syncthreads();
    }
    if (h == 0) logit[c] = red[0] + b_out[c];
    __syncthreads();
  }
  if (h == 0) {
    float mx = logit[0];
    for (int c = 1; c < NCLASS; ++c) mx = fmaxf(mx, logit[c]);
    float e[NCLASS], s = 0.f;
    for (int c = 0; c < NCLASS; ++c) { e[c] = expf(logit[c] - mx); s += e[c]; }
    float loss = 0.f;
    for (int c = 0; c < NCLASS; ++c) {
      float p = e[c] / s;
      out[c] = p;
      float d = y[c] - p;
      loss += d * d;
    }
    out[NCLASS] = loss;
  }
}

// ---------------------------------------------------------------- launch
extern "C" void kernel_launch(void* const* d_in, const int* in_sizes, int n_in,
                              void* d_out, int out_size, void* d_ws, size_t ws_size,
                              hipStream_t stream) {
  const int*   tree = (const int*)d_in[0];
  const int*   edge = (const int*)d_in[1];
  const int*   leaf = (const int*)d_in[2];
  const float* y    = (const float*)d_in[3];
  const float* E    = (const float*)d_in[4];
  const float* Wz   = (const float*)d_in[5];
  const float* Uz   = (const float*)d_in[6];
  const float* bz   = (const float*)d_in[7];
  const float* Wr   = (const float*)d_in[8];
  const float* Ur   = (const float*)d_in[9];
  const float* br   = (const float*)d_in[10];
  const float* Wh   = (const float*)d_in[11];
  const float* Uh   = (const float*)d_in[12];
  const float* bh   = (const float*)d_in[13];
  const float* Wout = (const float*)d_in[14];
  const float* bout = (const float*)d_in[15];
  float* out = (float*)d_out;

  char* base = (char*)d_ws;
  size_t b = 0;
  _Float16* ETh = (_Float16*)(base + b); b += (size_t)VOCAB * HID * 2;      // 25.7 MB
  b = (b + 255) & ~(size_t)255;
  half2_t* Upk = (half2_t*)(base + b); b += (size_t)6 * 4 * 8192 * 4;       // U(3) + W(3) packed
  half2_t* Hpk = (half2_t*)(base + b); b += (size_t)N_NODES * (HID / 2) * 4;
  float* H   = (float*)(base + b); b += (size_t)N_NODES * HID * 4;
  float* partial = (float*)(base + b); b += (size_t)64 * HID * 4;

  transpose_f16_kernel<<<dim3((VOCAB + 31) / 32, HID / 32), dim3(32, 8), 0, stream>>>(E, ETh, HID, VOCAB);
  pack_u_kernel<<<56, 256, 0, stream>>>(Uz, Ur, Uh, Wz, Wr, Wh, Upk, (unsigned*)Hpk);
  rnn_kernel<<<RNN_BLOCKS, 512, 0, stream>>>(tree, (const half2_t*)ETh, Upk,
                                             bz, br, bh, edge, H, (unsigned*)Hpk);
  leafmax_kernel<<<64, HID, 0, stream>>>(H, leaf, partial);
  final_kernel<<<1, HID, 0, stream>>>(partial, Wout, bout, y, out);
}

// Round 9
// 529.393 us; speedup vs baseline: 1.1707x; 1.0631x over previous
//
#include <hip/hip_runtime.h>
#include <math.h>

#define N_NODES 4096
#define WORDS   64
#define HID     256
#define VOCAB   50257
#define NCLASS  4
#define N_LEAF  2048
#define RNN_BLOCKS 256     // 1 block/CU -> all resident, spin-wait safe
#define POISON 0x7FFF7FFFu // half2 (NaN,NaN); finite packed rows never match
#define TR_BX   1571       // ceil(VOCAB/32)
#define TR_BLKS (TR_BX * (HID / 32))   // 12568 transpose role blocks

typedef _Float16 half2_t __attribute__((ext_vector_type(2)));

__device__ __forceinline__ float dot2f(half2_t a, half2_t b, float c) {
#if __has_builtin(__builtin_amdgcn_fdot2)
  return __builtin_amdgcn_fdot2(a, b, c, false);   // v_dot2_f32_f16
#else
  return c + (float)a.x * (float)b.x + (float)a.y * (float)b.y;
#endif
}

__device__ __forceinline__ half2_t f2h2(float f) {
  union { float f; half2_t h; } u; u.f = f; return u.h;
}

__device__ __forceinline__ float fast_rcp(float x) { return __builtin_amdgcn_rcpf(x); }
__device__ __forceinline__ float fast_sigmoid(float x) {        // rcp-based, no IEEE div seq
  return fast_rcp(1.f + __expf(-x));
}
__device__ __forceinline__ float fast_tanh(float x) {           // 1 - 2/(e^{2x}+1); saturates to +-1
  return 1.f - 2.f * fast_rcp(1.f + __expf(2.f * x));
}
__device__ __forceinline__ half2_t pkrtz(float a, float b) {    // single v_cvt_pkrtz_f16_f32
#if __has_builtin(__builtin_amdgcn_cvt_pkrtz)
  return __builtin_bit_cast(half2_t, __builtin_amdgcn_cvt_pkrtz(a, b));
#else
  half2_t v; v.x = (_Float16)a; v.y = (_Float16)b; return v;
#endif
}

// ---------------------------------------------------------------- prep: transpose | pack | poison (one grid)
// R19: merges transpose_f16 + pack_u + poison_hpk + counter-zero into a single launch.
// Roles by blockIdx: [0, TR_BLKS) transpose E->ETh; [TR_BLKS, +24) pack U/W; [+24, +56)
// poison Hpk (block +24, t0 also zeroes the leaffinal counter). LDS unioned (66.3 KB).
// All roles are mutually independent (pack reads Uz..Wh, transpose reads E, poison writes
// Hpk) -- previously 3 serialized launches.
__global__ void __launch_bounds__(256) prep_kernel(
    const float* __restrict__ E, _Float16* __restrict__ ETh,
    const float* __restrict__ Uz, const float* __restrict__ Ur, const float* __restrict__ Uh,
    const float* __restrict__ Wz, const float* __restrict__ Wr, const float* __restrict__ Wh,
    half2_t* __restrict__ Upk, unsigned* __restrict__ HpkU, unsigned* __restrict__ counter) {
  __shared__ float smem[64 * 259];           // union: transpose uses 32x33, pack uses 64x259
  const int t = threadIdx.x;
  int bb = blockIdx.x;

  if (bb < TR_BLKS) {
    // ---- transpose role: E (HID,VOCAB) f32 -> ETh (VOCAB,HID) f16
    float (*tile)[33] = (float(*)[33])smem;
    const int bx = bb % TR_BX, by = bb / TR_BX;
    const int c0 = bx * 32, r0 = by * 32;
    const int tx = t & 31, ty = t >> 5;      // 32x8 (reshaped from dim3(32,8))
#pragma unroll
    for (int j = 0; j < 32; j += 8) {
      int c = c0 + tx, r = r0 + ty + j;
      if (c < VOCAB) tile[ty + j][tx] = E[(size_t)r * VOCAB + c];
    }
    __syncthreads();
#pragma unroll
    for (int j = 0; j < 32; j += 8) {
      int c = c0 + ty + j, r = r0 + tx;
      if (c < VOCAB) ETh[(size_t)c * HID + r] = (_Float16)tile[tx][ty + j];
    }
    return;
  }
  bb -= TR_BLKS;

  if (bb < 24) {
    // ---- pack role: packed[m][kp][h] = (M[h][2kp], M[h][2kp+1]), idx (m*4+s)*8192+j*256+h
    float (*tile)[259] = (float(*)[259])smem;
    const int m = bb >> 2, g = bb & 3;
    const float* U = m == 0 ? Uz : (m == 1 ? Ur : (m == 2 ? Uh : (m == 3 ? Wz : (m == 4 ? Wr : Wh))));
    for (int r = 0; r < 64; ++r) tile[r][t] = U[(size_t)(g * 64 + r) * 256 + t];
    __syncthreads();
#pragma unroll
    for (int it = 0; it < 32; ++it) {
      int e = it * 256 + t;
      int hl = e & 63, kj = e >> 6, s = kj >> 5, j = kj & 31;
      half2_t v;
      v.x = (_Float16)tile[hl][s * 64 + 2 * j];
      v.y = (_Float16)tile[hl][s * 64 + 2 * j + 1];
      Upk[(size_t)(m * 4 + s) * 8192 + j * 256 + (g * 64 + hl)] = v;
    }
    return;
  }
  bb -= 24;

  // ---- poison role: 32 blocks x 16384 words cover N_NODES*(HID/2)
  if (bb == 0 && t == 0) *counter = 0u;      // leaffinal completion counter (re-run safe)
  const int base = bb * 16384 + t;
#pragma unroll
  for (int k = 0; k < 64; ++k) HpkU[base + k * 256] = POISON;
}

// ---------------------------------------------------------------- fused gather + 3-gate GEMV
// R15 verbatim (proven 1024-block geometry; R18 showed fusing this into rnn's 256-block
// grid costs 2x on the same work). One block per 4 nodes, 256 threads.
__global__ void __launch_bounds__(256) gather_gemv_kernel(
    const int* __restrict__ tree, const half2_t* __restrict__ ETh2,
    const half2_t* __restrict__ Upk,
    float* __restrict__ Az, float* __restrict__ Ar, float* __restrict__ Ah,
    float* __restrict__ H, half2_t* __restrict__ Hpk) {
  const int t  = threadIdx.x;
  const int i0 = blockIdx.x * 4;
  __shared__ int     vsf[4 * WORDS];       // 4 nodes' word ids (contiguous in tree)
  __shared__ float2  ps[256];              // gather partial sums
  __shared__ half2_t Xh[4][HID / 2];       // 4 nodes' X rows, f16 pairs

  vsf[t] = tree[(size_t)i0 * WORDS + t];   // 4*64 = 256 words, coalesced
  __syncthreads();

  const int c    = t & 127;                // half2 column
  const int half = t >> 7;                 // word-half
#pragma unroll
  for (int n = 0; n < 4; ++n) {
    float ax = 0.f, ay = 0.f;
    const int base = n * WORDS + half * 32;
#pragma unroll 8
    for (int w = 0; w < 32; ++w) {
      half2_t e = ETh2[(size_t)vsf[base + w] * (HID / 2) + c];
      ax += (float)e.x;
      ay += (float)e.y;
    }
    ps[t].x = ax; ps[t].y = ay;
    __syncthreads();
    if (t < 128) {
      float xx = ps[t].x + ps[t + 128].x;
      float yy = ps[t].y + ps[t + 128].y;
      half2_t hv; hv.x = (_Float16)xx; hv.y = (_Float16)yy;   // RNE casts (match old gather)
      Xh[n][t] = hv;
      if (i0 + n == 0) {                   // node 0: seed fp32 H row + packed Hpk row
        float2 v2; v2.x = xx; v2.y = yy;
        ((float2*)H)[t] = v2;
        Hpk[t] = hv;
      }
    }
    __syncthreads();                       // ps reusable; Xh[n] visible to all
  }

  // ---- GEMV: 3 gates x 4 nodes, output neuron = t
  float acc[3][4];
#pragma unroll
  for (int m = 0; m < 3; ++m)
#pragma unroll
    for (int n = 0; n < 4; ++n) acc[m][n] = 0.f;

  const half2_t* wb = Upk + (size_t)12 * 8192 + t;   // m=3 (Wz) base, +32768 per gate
#pragma unroll 8
  for (int kp = 0; kp < 128; ++kp) {
    half2_t w0 = wb[kp * 256];
    half2_t w1 = wb[kp * 256 + 32768];
    half2_t w2 = wb[kp * 256 + 65536];
    half2_t x0 = Xh[0][kp], x1 = Xh[1][kp], x2 = Xh[2][kp], x3 = Xh[3][kp];  // LDS broadcast
    acc[0][0] = dot2f(w0, x0, acc[0][0]); acc[0][1] = dot2f(w0, x1, acc[0][1]);
    acc[0][2] = dot2f(w0, x2, acc[0][2]); acc[0][3] = dot2f(w0, x3, acc[0][3]);
    acc[1][0] = dot2f(w1, x0, acc[1][0]); acc[1][1] = dot2f(w1, x1, acc[1][1]);
    acc[1][2] = dot2f(w1, x2, acc[1][2]); acc[1][3] = dot2f(w1, x3, acc[1][3]);
    acc[2][0] = dot2f(w2, x0, acc[2][0]); acc[2][1] = dot2f(w2, x1, acc[2][1]);
    acc[2][2] = dot2f(w2, x2, acc[2][2]); acc[2][3] = dot2f(w2, x3, acc[2][3]);
  }
#pragma unroll
  for (int n = 0; n < 4; ++n) {
    Az[(size_t)(i0 + n) * HID + t] = acc[0][n];
    Ar[(size_t)(i0 + n) * HID + t] = acc[1][n];
    Ah[(size_t)(i0 + n) * HID + t] = acc[2][n];
  }
}

// ---------------------------------------------------------------- persistent wavefront GRU scan (block-cyclic)
// R19 = R15's scan BYTE-IDENTICAL (empirical floor ~352us after 6 failed redesigns:
// R1 serialization, R12 duplication, R14 chain-lengthening, R16 re-shard, R17 pairing,
// R18 prologue-fusion). R9 protocol + R10 fast epilogue; spin escape 1<<22.
// All U loops FULLY unrolled (R6 lesson: partial unroll -> alloca -> LDS/scratch catastrophe).
__global__ void
__attribute__((amdgpu_flat_work_group_size(512, 512), amdgpu_waves_per_eu(2, 2)))
rnn_kernel(
    const float* __restrict__ Az, const float* __restrict__ Ar, const float* __restrict__ Ah,
    const half2_t* __restrict__ Upk,
    const float* __restrict__ bz, const float* __restrict__ br, const float* __restrict__ bh,
    const int* __restrict__ edge, float* __restrict__ H, unsigned* HpkU) {
  const int tid = threadIdx.x;
  const int h   = tid & (HID - 1);
  const int ks  = tid >> 8;            // 0..1
  __shared__ half2_t php[HID / 2];
  __shared__ half2_t rhp[HID / 2];
  __shared__ float   part[2 * HID];

  // one-time U load (full unroll -> SSA -> register file)
  half2_t um[128];   // Uz (ks0) or Ur (ks1), full K
  half2_t uhh[64];   // Uh, k-slice [ks*128, ks*128+128)
  {
    const half2_t* mb = Upk + (size_t)(ks ? 4 : 0) * 8192 + h;
#pragma unroll
    for (int j = 0; j < 128; ++j)
      um[j] = mb[(j >> 5) * 8192 + (j & 31) * 256];
    const half2_t* hb = Upk + (size_t)(8 + 2 * ks) * 8192 + h;
#pragma unroll
    for (int j = 0; j < 64; ++j)
      uhh[j] = hb[(j >> 5) * 8192 + (j & 31) * 256];
  }
  const float b1  = ks ? br[h] : bz[h];
  const float bhv = ks ? 0.f : bh[h];

  const int istart = blockIdx.x == 0 ? RNN_BLOCKS : blockIdx.x;  // node 0 pre-seeded by gather
  for (int i = istart; i < N_NODES; i += RNN_BLOCKS) {
    const int p = edge[2 * i];   // parent, p < i
    // A-row loads issued before the poll; they complete while waiting
    const float a1 = ks ? Ar[(size_t)i * HID + h] : Az[(size_t)i * HID + h];
    const float a2 = ks ? 0.f : Ah[(size_t)i * HID + h];

    if (tid < HID / 2) {
      unsigned v = __hip_atomic_load(&HpkU[(size_t)p * (HID / 2) + tid],
                                     __ATOMIC_RELAXED, __HIP_MEMORY_SCOPE_AGENT);
      long spin = 0;
      while (v == POISON) {
        if (++spin > (1L << 22)) break;   // escape hatch (should never trigger)
        v = __hip_atomic_load(&HpkU[(size_t)p * (HID / 2) + tid],
                              __ATOMIC_RELAXED, __HIP_MEMORY_SCOPE_AGENT);
      }
      php[tid] = __builtin_bit_cast(half2_t, v);
    }
    __syncthreads();   // B0: packed parent row resident in LDS

    // parent element for this h, decoded from fp16 row
    half2_t ph2 = php[h >> 1];
    const float phv = (float)((h & 1) ? ph2.y : ph2.x);

    // phase 1: full-K dot of Uz (ks0) / Ur (ks1) against packed parent row
    float ac0 = a1 + b1, ac1 = 0.f, ac2 = 0.f, ac3 = 0.f;
    {
      const float4* phq = (const float4*)php;
#pragma unroll
      for (int q = 0; q < 32; ++q) {
        float4 blk = phq[q];
        ac0 = dot2f(um[4 * q + 0], f2h2(blk.x), ac0);
        ac1 = dot2f(um[4 * q + 1], f2h2(blk.y), ac1);
        ac2 = dot2f(um[4 * q + 2], f2h2(blk.z), ac2);
        ac3 = dot2f(um[4 * q + 3], f2h2(blk.w), ac3);
      }
    }
    const float g = fast_sigmoid((ac0 + ac1) + (ac2 + ac3));
    if (ks) {                    // r gate -> packed r*ph
      float rh = g * phv;
      float nb = __shfl_xor(rh, 1, 64);
      if ((h & 1) == 0) rhp[h >> 1] = pkrtz(rh, nb);
    }
    __syncthreads();   // B1

    // phase 2: Uh partial dots over this thread's k-slice
    float c0 = 0.f, c1 = 0.f;
    {
      const float4* rq = (const float4*)(rhp + ks * 64);
#pragma unroll
      for (int q = 0; q < 16; ++q) {
        float4 blk = rq[q];
        c0 = dot2f(uhh[4 * q + 0], f2h2(blk.x), c0);
        c1 = dot2f(uhh[4 * q + 1], f2h2(blk.y), c1);
        c0 = dot2f(uhh[4 * q + 2], f2h2(blk.z), c0);
        c1 = dot2f(uhh[4 * q + 3], f2h2(blk.w), c1);
      }
    }
    part[ks * HID + h] = c0 + c1;
    __syncthreads();   // B2

    if (ks == 0) {
      float ca = a2 + bhv + part[h] + part[HID + h];
      float c  = fast_tanh(ca);
      float hn = fmaf(g, phv, (1.f - g) * c);
      float nb = __shfl_xor(hn, 1, 64);   // DPP xor-1
      if ((h & 1) == 0) {                 // handoff store FIRST (children poll this)
        __hip_atomic_store(&HpkU[(size_t)i * (HID / 2) + (h >> 1)],
                           __builtin_bit_cast(unsigned, pkrtz(hn, nb)),
                           __ATOMIC_RELAXED, __HIP_MEMORY_SCOPE_AGENT);
      }
      H[(size_t)i * HID + h] = hn;        // fp32 row for leafmax (off critical path)
    }
    // no publish barrier, no waitcnt, no flag: the row stores are the signal
  }
}

// ---------------------------------------------------------------- leafmax + final, fused (last-block pattern)
// R19: 64 blocks compute partial leaf-maxes; the last block to finish (device-scope
// counter) runs the final W_out/softmax/loss. Saves a launch gap + partial round-trip gap.
// Counter zeroed by prep each run (re-run safe). threadfence release/acquire brackets the
// partial stores (standard pattern; rnn's protocol already relies on cross-XCD visibility).
__global__ void leaffinal_kernel(const float* __restrict__ H, const int* __restrict__ leafs,
                                 const float* __restrict__ W_out, const float* __restrict__ b_out,
                                 const float* __restrict__ y,
                                 float* __restrict__ partial, unsigned* __restrict__ counter,
                                 float* __restrict__ out) {
  const int b = blockIdx.x;
  const int h = threadIdx.x;
  float m = -INFINITY;
#pragma unroll 4
  for (int j = 0; j < N_LEAF / 64; ++j) {
    int node = leafs[b * (N_LEAF / 64) + j];
    m = fmaxf(m, H[(size_t)node * HID + h]);
  }
  partial[b * HID + h] = m;
  __threadfence();                       // release partial stores (device scope)
  __syncthreads();
  __shared__ int last;
  if (h == 0) last = (atomicAdd(counter, 1u) == 63u);
  __syncthreads();
  if (!last) return;
  __threadfence();                       // acquire other blocks' partials

  float mm = -INFINITY;
#pragma unroll 8
  for (int bb = 0; bb < 64; ++bb) mm = fmaxf(mm, partial[bb * HID + h]);
  __shared__ float fs[HID];
  __shared__ float red[HID];
  __shared__ float logit[NCLASS];
  fs[h] = mm;
  __syncthreads();
  for (int c = 0; c < NCLASS; ++c) {
    red[h] = W_out[c * HID + h] * fs[h];
    __syncthreads();
    for (int s = HID / 2; s > 0; s >>= 1) {
      if (h < s) red[h] += red[h + s];
      __syncthreads();
    }
    if (h == 0) logit[c] = red[0] + b_out[c];
    __syncthreads();
  }
  if (h == 0) {
    float mx = logit[0];
    for (int c = 1; c < NCLASS; ++c) mx = fmaxf(mx, logit[c]);
    float e[NCLASS], s = 0.f;
    for (int c = 0; c < NCLASS; ++c) { e[c] = expf(logit[c] - mx); s += e[c]; }
    float loss = 0.f;
    for (int c = 0; c < NCLASS; ++c) {
      float p = e[c] / s;
      out[c] = p;
      float d = y[c] - p;
      loss += d * d;
    }
    out[NCLASS] = loss;
  }
}

// ---------------------------------------------------------------- launch
extern "C" void kernel_launch(void* const* d_in, const int* in_sizes, int n_in,
                              void* d_out, int out_size, void* d_ws, size_t ws_size,
                              hipStream_t stream) {
  const int*   tree = (const int*)d_in[0];
  const int*   edge = (const int*)d_in[1];
  const int*   leaf = (const int*)d_in[2];
  const float* y    = (const float*)d_in[3];
  const float* E    = (const float*)d_in[4];
  const float* Wz   = (const float*)d_in[5];
  const float* Uz   = (const float*)d_in[6];
  const float* bz   = (const float*)d_in[7];
  const float* Wr   = (const float*)d_in[8];
  const float* Ur   = (const float*)d_in[9];
  const float* br   = (const float*)d_in[10];
  const float* Wh   = (const float*)d_in[11];
  const float* Uh   = (const float*)d_in[12];
  const float* bh   = (const float*)d_in[13];
  const float* Wout = (const float*)d_in[14];
  const float* bout = (const float*)d_in[15];
  float* out = (float*)d_out;

  char* base = (char*)d_ws;
  size_t b = 0;
  _Float16* ETh = (_Float16*)(base + b); b += (size_t)VOCAB * HID * 2;      // 25.7 MB
  b = (b + 255) & ~(size_t)255;
  half2_t* Upk = (half2_t*)(base + b); b += (size_t)6 * 4 * 8192 * 4;       // U(3) + W(3) packed
  half2_t* Hpk = (half2_t*)(base + b); b += (size_t)N_NODES * (HID / 2) * 4;
  float* Az  = (float*)(base + b); b += (size_t)N_NODES * HID * 4;
  float* Ar  = (float*)(base + b); b += (size_t)N_NODES * HID * 4;
  float* Ah  = (float*)(base + b); b += (size_t)N_NODES * HID * 4;
  float* H   = (float*)(base + b); b += (size_t)N_NODES * HID * 4;
  float* partial = (float*)(base + b); b += (size_t)64 * HID * 4;
  unsigned* counter = (unsigned*)(base + b); b += 256;

  prep_kernel<<<TR_BLKS + 24 + 32, 256, 0, stream>>>(E, ETh, Uz, Ur, Uh, Wz, Wr, Wh,
                                                     Upk, (unsigned*)Hpk, counter);
  gather_gemv_kernel<<<N_NODES / 4, 256, 0, stream>>>(tree, (const half2_t*)ETh, Upk,
                                                      Az, Ar, Ah, H, Hpk);
  rnn_kernel<<<RNN_BLOCKS, 512, 0, stream>>>(Az, Ar, Ah, Upk, bz, br, bh, edge, H, (unsigned*)Hpk);
  leaffinal_kernel<<<64, HID, 0, stream>>>(H, leaf, Wout, bout, y, partial, counter, out);
}

// Round 10
// 514.666 us; speedup vs baseline: 1.2042x; 1.0286x over previous
//
#include <hip/hip_runtime.h>
#include <math.h>

#define N_NODES 4096
#define WORDS   64
#define HID     256
#define VOCAB   50257
#define NCLASS  4
#define N_LEAF  2048
#define RNN_BLOCKS 256     // 1 block/CU -> all resident, spin-wait safe
#define POISON 0x7FFF7FFFu // half2 (NaN,NaN); finite packed rows never match
#define TR_BX   1571       // ceil(VOCAB/32)
#define TR_BLKS (TR_BX * (HID / 32))   // 12568 transpose role blocks
#define PK_BLKS 96         // pack role blocks (LDS-free)
#define PO_BLKS 32         // poison role blocks (LDS-free)

typedef _Float16 half2_t __attribute__((ext_vector_type(2)));

__device__ __forceinline__ float dot2f(half2_t a, half2_t b, float c) {
#if __has_builtin(__builtin_amdgcn_fdot2)
  return __builtin_amdgcn_fdot2(a, b, c, false);   // v_dot2_f32_f16
#else
  return c + (float)a.x * (float)b.x + (float)a.y * (float)b.y;
#endif
}

__device__ __forceinline__ half2_t f2h2(float f) {
  union { float f; half2_t h; } u; u.f = f; return u.h;
}

__device__ __forceinline__ float fast_rcp(float x) { return __builtin_amdgcn_rcpf(x); }
__device__ __forceinline__ float fast_sigmoid(float x) {        // rcp-based, no IEEE div seq
  return fast_rcp(1.f + __expf(-x));
}
__device__ __forceinline__ float fast_tanh(float x) {           // 1 - 2/(e^{2x}+1); saturates to +-1
  return 1.f - 2.f * fast_rcp(1.f + __expf(2.f * x));
}
__device__ __forceinline__ half2_t pkrtz(float a, float b) {    // single v_cvt_pkrtz_f16_f32
#if __has_builtin(__builtin_amdgcn_cvt_pkrtz)
  return __builtin_bit_cast(half2_t, __builtin_amdgcn_cvt_pkrtz(a, b));
#else
  half2_t v; v.x = (_Float16)a; v.y = (_Float16)b; return v;
#endif
}

// ---------------------------------------------------------------- prep: pack | poison | transpose (one grid)
// R20: R19's prep regressed the transpose 4x because the pack role's 66.3KB LDS union was
// allocated by ALL 12568 transpose blocks (2 blocks/CU instead of 8 -- occupancy own-goal).
// Fix: pack is LDS-FREE -- thread t=h reads U[h][16*kpg .. 16*kpg+16) as 4x float4 (one
// cache line per thread, zero amplification; index algebra: Upk linear = m*32768 + kp*256
// + h with value (U[h][2kp], U[h][2kp+1]), kp = 8*kpg + kk, 2kp = 16*kpg + 2*kk) and
// writes 8 half2 coalesced in t. Poison/counter role also LDS-free. Max LDS = transpose's
// 4.2KB tile -> full occupancy. Small roles dispatch FIRST so they hide under transpose.
// RNE (_Float16) casts match the old pack exactly.
__global__ void __launch_bounds__(256) prep_kernel(
    const float* __restrict__ E, _Float16* __restrict__ ETh,
    const float* __restrict__ Uz, const float* __restrict__ Ur, const float* __restrict__ Uh,
    const float* __restrict__ Wz, const float* __restrict__ Wr, const float* __restrict__ Wh,
    half2_t* __restrict__ Upk, unsigned* __restrict__ HpkU, unsigned* __restrict__ counter) {
  __shared__ float tile[32][33];             // used by transpose role only (4.2 KB)
  const int t = threadIdx.x;
  int bb = blockIdx.x;

  if (bb < PK_BLKS) {
    // ---- pack role (LDS-free): m = bb>>4, kpg = bb&15; thread t = h
    const int m = bb >> 4, kpg = bb & 15;
    const float* U = m == 0 ? Uz : (m == 1 ? Ur : (m == 2 ? Uh : (m == 3 ? Wz : (m == 4 ? Wr : Wh))));
    const float* src = U + (size_t)t * 256 + kpg * 16;   // 64B-aligned, one line per thread
    float4 f0 = *(const float4*)(src + 0);
    float4 f1 = *(const float4*)(src + 4);
    float4 f2 = *(const float4*)(src + 8);
    float4 f3 = *(const float4*)(src + 12);
    half2_t* dst = Upk + (size_t)m * 32768 + (size_t)(kpg * 8) * 256 + t;
    half2_t v;
    v.x = (_Float16)f0.x; v.y = (_Float16)f0.y; dst[0 * 256] = v;
    v.x = (_Float16)f0.z; v.y = (_Float16)f0.w; dst[1 * 256] = v;
    v.x = (_Float16)f1.x; v.y = (_Float16)f1.y; dst[2 * 256] = v;
    v.x = (_Float16)f1.z; v.y = (_Float16)f1.w; dst[3 * 256] = v;
    v.x = (_Float16)f2.x; v.y = (_Float16)f2.y; dst[4 * 256] = v;
    v.x = (_Float16)f2.z; v.y = (_Float16)f2.w; dst[5 * 256] = v;
    v.x = (_Float16)f3.x; v.y = (_Float16)f3.y; dst[6 * 256] = v;
    v.x = (_Float16)f3.z; v.y = (_Float16)f3.w; dst[7 * 256] = v;
    return;
  }
  bb -= PK_BLKS;

  if (bb < PO_BLKS) {
    // ---- poison role (LDS-free): 32 blocks x 16384 words cover N_NODES*(HID/2)
    if (bb == 0 && t == 0) *counter = 0u;    // leaffinal completion counter (re-run safe)
    const int base = bb * 16384 + t;
#pragma unroll
    for (int k = 0; k < 64; ++k) HpkU[base + k * 256] = POISON;
    return;
  }
  bb -= PO_BLKS;

  // ---- transpose role: E (HID,VOCAB) f32 -> ETh (VOCAB,HID) f16
  const int bx = bb % TR_BX, by = bb / TR_BX;
  const int c0 = bx * 32, r0 = by * 32;
  const int tx = t & 31, ty = t >> 5;        // 32x8 (reshaped from dim3(32,8))
#pragma unroll
  for (int j = 0; j < 32; j += 8) {
    int c = c0 + tx, r = r0 + ty + j;
    if (c < VOCAB) tile[ty + j][tx] = E[(size_t)r * VOCAB + c];
  }
  __syncthreads();
#pragma unroll
  for (int j = 0; j < 32; j += 8) {
    int c = c0 + ty + j, r = r0 + tx;
    if (c < VOCAB) ETh[(size_t)c * HID + r] = (_Float16)tile[tx][ty + j];
  }
}

// ---------------------------------------------------------------- fused gather + 3-gate GEMV
// R15 verbatim (proven 1024-block geometry; R18 showed fusing this into rnn's 256-block
// grid costs 2x on the same work). One block per 4 nodes, 256 threads.
__global__ void __launch_bounds__(256) gather_gemv_kernel(
    const int* __restrict__ tree, const half2_t* __restrict__ ETh2,
    const half2_t* __restrict__ Upk,
    float* __restrict__ Az, float* __restrict__ Ar, float* __restrict__ Ah,
    float* __restrict__ H, half2_t* __restrict__ Hpk) {
  const int t  = threadIdx.x;
  const int i0 = blockIdx.x * 4;
  __shared__ int     vsf[4 * WORDS];       // 4 nodes' word ids (contiguous in tree)
  __shared__ float2  ps[256];              // gather partial sums
  __shared__ half2_t Xh[4][HID / 2];       // 4 nodes' X rows, f16 pairs

  vsf[t] = tree[(size_t)i0 * WORDS + t];   // 4*64 = 256 words, coalesced
  __syncthreads();

  const int c    = t & 127;                // half2 column
  const int half = t >> 7;                 // word-half
#pragma unroll
  for (int n = 0; n < 4; ++n) {
    float ax = 0.f, ay = 0.f;
    const int base = n * WORDS + half * 32;
#pragma unroll 8
    for (int w = 0; w < 32; ++w) {
      half2_t e = ETh2[(size_t)vsf[base + w] * (HID / 2) + c];
      ax += (float)e.x;
      ay += (float)e.y;
    }
    ps[t].x = ax; ps[t].y = ay;
    __syncthreads();
    if (t < 128) {
      float xx = ps[t].x + ps[t + 128].x;
      float yy = ps[t].y + ps[t + 128].y;
      half2_t hv; hv.x = (_Float16)xx; hv.y = (_Float16)yy;   // RNE casts (match old gather)
      Xh[n][t] = hv;
      if (i0 + n == 0) {                   // node 0: seed fp32 H row + packed Hpk row
        float2 v2; v2.x = xx; v2.y = yy;
        ((float2*)H)[t] = v2;
        Hpk[t] = hv;
      }
    }
    __syncthreads();                       // ps reusable; Xh[n] visible to all
  }

  // ---- GEMV: 3 gates x 4 nodes, output neuron = t
  float acc[3][4];
#pragma unroll
  for (int m = 0; m < 3; ++m)
#pragma unroll
    for (int n = 0; n < 4; ++n) acc[m][n] = 0.f;

  const half2_t* wb = Upk + (size_t)12 * 8192 + t;   // m=3 (Wz) base, +32768 per gate
#pragma unroll 8
  for (int kp = 0; kp < 128; ++kp) {
    half2_t w0 = wb[kp * 256];
    half2_t w1 = wb[kp * 256 + 32768];
    half2_t w2 = wb[kp * 256 + 65536];
    half2_t x0 = Xh[0][kp], x1 = Xh[1][kp], x2 = Xh[2][kp], x3 = Xh[3][kp];  // LDS broadcast
    acc[0][0] = dot2f(w0, x0, acc[0][0]); acc[0][1] = dot2f(w0, x1, acc[0][1]);
    acc[0][2] = dot2f(w0, x2, acc[0][2]); acc[0][3] = dot2f(w0, x3, acc[0][3]);
    acc[1][0] = dot2f(w1, x0, acc[1][0]); acc[1][1] = dot2f(w1, x1, acc[1][1]);
    acc[1][2] = dot2f(w1, x2, acc[1][2]); acc[1][3] = dot2f(w1, x3, acc[1][3]);
    acc[2][0] = dot2f(w2, x0, acc[2][0]); acc[2][1] = dot2f(w2, x1, acc[2][1]);
    acc[2][2] = dot2f(w2, x2, acc[2][2]); acc[2][3] = dot2f(w2, x3, acc[2][3]);
  }
#pragma unroll
  for (int n = 0; n < 4; ++n) {
    Az[(size_t)(i0 + n) * HID + t] = acc[0][n];
    Ar[(size_t)(i0 + n) * HID + t] = acc[1][n];
    Ah[(size_t)(i0 + n) * HID + t] = acc[2][n];
  }
}

// ---------------------------------------------------------------- persistent wavefront GRU scan (block-cyclic)
// R20 = R15's scan BYTE-IDENTICAL (empirical floor ~334-352us after 6 failed redesigns:
// R1 serialization, R12 duplication, R14 chain-lengthening, R16 re-shard, R17 pairing,
// R18 prologue-fusion). R9 protocol + R10 fast epilogue; spin escape 1<<22.
// All U loops FULLY unrolled (R6 lesson: partial unroll -> alloca -> LDS/scratch catastrophe).
__global__ void
__attribute__((amdgpu_flat_work_group_size(512, 512), amdgpu_waves_per_eu(2, 2)))
rnn_kernel(
    const float* __restrict__ Az, const float* __restrict__ Ar, const float* __restrict__ Ah,
    const half2_t* __restrict__ Upk,
    const float* __restrict__ bz, const float* __restrict__ br, const float* __restrict__ bh,
    const int* __restrict__ edge, float* __restrict__ H, unsigned* HpkU) {
  const int tid = threadIdx.x;
  const int h   = tid & (HID - 1);
  const int ks  = tid >> 8;            // 0..1
  __shared__ half2_t php[HID / 2];
  __shared__ half2_t rhp[HID / 2];
  __shared__ float   part[2 * HID];

  // one-time U load (full unroll -> SSA -> register file)
  half2_t um[128];   // Uz (ks0) or Ur (ks1), full K
  half2_t uhh[64];   // Uh, k-slice [ks*128, ks*128+128)
  {
    const half2_t* mb = Upk + (size_t)(ks ? 4 : 0) * 8192 + h;
#pragma unroll
    for (int j = 0; j < 128; ++j)
      um[j] = mb[(j >> 5) * 8192 + (j & 31) * 256];
    const half2_t* hb = Upk + (size_t)(8 + 2 * ks) * 8192 + h;
#pragma unroll
    for (int j = 0; j < 64; ++j)
      uhh[j] = hb[(j >> 5) * 8192 + (j & 31) * 256];
  }
  const float b1  = ks ? br[h] : bz[h];
  const float bhv = ks ? 0.f : bh[h];

  const int istart = blockIdx.x == 0 ? RNN_BLOCKS : blockIdx.x;  // node 0 pre-seeded by gather
  for (int i = istart; i < N_NODES; i += RNN_BLOCKS) {
    const int p = edge[2 * i];   // parent, p < i
    // A-row loads issued before the poll; they complete while waiting
    const float a1 = ks ? Ar[(size_t)i * HID + h] : Az[(size_t)i * HID + h];
    const float a2 = ks ? 0.f : Ah[(size_t)i * HID + h];

    if (tid < HID / 2) {
      unsigned v = __hip_atomic_load(&HpkU[(size_t)p * (HID / 2) + tid],
                                     __ATOMIC_RELAXED, __HIP_MEMORY_SCOPE_AGENT);
      long spin = 0;
      while (v == POISON) {
        if (++spin > (1L << 22)) break;   // escape hatch (should never trigger)
        v = __hip_atomic_load(&HpkU[(size_t)p * (HID / 2) + tid],
                              __ATOMIC_RELAXED, __HIP_MEMORY_SCOPE_AGENT);
      }
      php[tid] = __builtin_bit_cast(half2_t, v);
    }
    __syncthreads();   // B0: packed parent row resident in LDS

    // parent element for this h, decoded from fp16 row
    half2_t ph2 = php[h >> 1];
    const float phv = (float)((h & 1) ? ph2.y : ph2.x);

    // phase 1: full-K dot of Uz (ks0) / Ur (ks1) against packed parent row
    float ac0 = a1 + b1, ac1 = 0.f, ac2 = 0.f, ac3 = 0.f;
    {
      const float4* phq = (const float4*)php;
#pragma unroll
      for (int q = 0; q < 32; ++q) {
        float4 blk = phq[q];
        ac0 = dot2f(um[4 * q + 0], f2h2(blk.x), ac0);
        ac1 = dot2f(um[4 * q + 1], f2h2(blk.y), ac1);
        ac2 = dot2f(um[4 * q + 2], f2h2(blk.z), ac2);
        ac3 = dot2f(um[4 * q + 3], f2h2(blk.w), ac3);
      }
    }
    const float g = fast_sigmoid((ac0 + ac1) + (ac2 + ac3));
    if (ks) {                    // r gate -> packed r*ph
      float rh = g * phv;
      float nb = __shfl_xor(rh, 1, 64);
      if ((h & 1) == 0) rhp[h >> 1] = pkrtz(rh, nb);
    }
    __syncthreads();   // B1

    // phase 2: Uh partial dots over this thread's k-slice
    float c0 = 0.f, c1 = 0.f;
    {
      const float4* rq = (const float4*)(rhp + ks * 64);
#pragma unroll
      for (int q = 0; q < 16; ++q) {
        float4 blk = rq[q];
        c0 = dot2f(uhh[4 * q + 0], f2h2(blk.x), c0);
        c1 = dot2f(uhh[4 * q + 1], f2h2(blk.y), c1);
        c0 = dot2f(uhh[4 * q + 2], f2h2(blk.z), c0);
        c1 = dot2f(uhh[4 * q + 3], f2h2(blk.w), c1);
      }
    }
    part[ks * HID + h] = c0 + c1;
    __syncthreads();   // B2

    if (ks == 0) {
      float ca = a2 + bhv + part[h] + part[HID + h];
      float c  = fast_tanh(ca);
      float hn = fmaf(g, phv, (1.f - g) * c);
      float nb = __shfl_xor(hn, 1, 64);   // DPP xor-1
      if ((h & 1) == 0) {                 // handoff store FIRST (children poll this)
        __hip_atomic_store(&HpkU[(size_t)i * (HID / 2) + (h >> 1)],
                           __builtin_bit_cast(unsigned, pkrtz(hn, nb)),
                           __ATOMIC_RELAXED, __HIP_MEMORY_SCOPE_AGENT);
      }
      H[(size_t)i * HID + h] = hn;        // fp32 row for leafmax (off critical path)
    }
    // no publish barrier, no waitcnt, no flag: the row stores are the signal
  }
}

// ---------------------------------------------------------------- leafmax + final, fused (last-block pattern)
// R19 (kept): 64 blocks compute partial leaf-maxes; the last block (device-scope counter)
// runs the final W_out/softmax/loss. Counter zeroed by prep each run (re-run safe).
__global__ void leaffinal_kernel(const float* __restrict__ H, const int* __restrict__ leafs,
                                 const float* __restrict__ W_out, const float* __restrict__ b_out,
                                 const float* __restrict__ y,
                                 float* __restrict__ partial, unsigned* __restrict__ counter,
                                 float* __restrict__ out) {
  const int b = blockIdx.x;
  const int h = threadIdx.x;
  float m = -INFINITY;
#pragma unroll 4
  for (int j = 0; j < N_LEAF / 64; ++j) {
    int node = leafs[b * (N_LEAF / 64) + j];
    m = fmaxf(m, H[(size_t)node * HID + h]);
  }
  partial[b * HID + h] = m;
  __threadfence();                       // release partial stores (device scope)
  __syncthreads();
  __shared__ int last;
  if (h == 0) last = (atomicAdd(counter, 1u) == 63u);
  __syncthreads();
  if (!last) return;
  __threadfence();                       // acquire other blocks' partials

  float mm = -INFINITY;
#pragma unroll 8
  for (int bb = 0; bb < 64; ++bb) mm = fmaxf(mm, partial[bb * HID + h]);
  __shared__ float fs[HID];
  __shared__ float red[HID];
  __shared__ float logit[NCLASS];
  fs[h] = mm;
  __syncthreads();
  for (int c = 0; c < NCLASS; ++c) {
    red[h] = W_out[c * HID + h] * fs[h];
    __syncthreads();
    for (int s = HID / 2; s > 0; s >>= 1) {
      if (h < s) red[h] += red[h + s];
      __syncthreads();
    }
    if (h == 0) logit[c] = red[0] + b_out[c];
    __syncthreads();
  }
  if (h == 0) {
    float mx = logit[0];
    for (int c = 1; c < NCLASS; ++c) mx = fmaxf(mx, logit[c]);
    float e[NCLASS], s = 0.f;
    for (int c = 0; c < NCLASS; ++c) { e[c] = expf(logit[c] - mx); s += e[c]; }
    float loss = 0.f;
    for (int c = 0; c < NCLASS; ++c) {
      float p = e[c] / s;
      out[c] = p;
      float d = y[c] - p;
      loss += d * d;
    }
    out[NCLASS] = loss;
  }
}

// ---------------------------------------------------------------- launch
extern "C" void kernel_launch(void* const* d_in, const int* in_sizes, int n_in,
                              void* d_out, int out_size, void* d_ws, size_t ws_size,
                              hipStream_t stream) {
  const int*   tree = (const int*)d_in[0];
  const int*   edge = (const int*)d_in[1];
  const int*   leaf = (const int*)d_in[2];
  const float* y    = (const float*)d_in[3];
  const float* E    = (const float*)d_in[4];
  const float* Wz   = (const float*)d_in[5];
  const float* Uz   = (const float*)d_in[6];
  const float* bz   = (const float*)d_in[7];
  const float* Wr   = (const float*)d_in[8];
  const float* Ur   = (const float*)d_in[9];
  const float* br   = (const float*)d_in[10];
  const float* Wh   = (const float*)d_in[11];
  const float* Uh   = (const float*)d_in[12];
  const float* bh   = (const float*)d_in[13];
  const float* Wout = (const float*)d_in[14];
  const float* bout = (const float*)d_in[15];
  float* out = (float*)d_out;

  char* base = (char*)d_ws;
  size_t b = 0;
  _Float16* ETh = (_Float16*)(base + b); b += (size_t)VOCAB * HID * 2;      // 25.7 MB
  b = (b + 255) & ~(size_t)255;
  half2_t* Upk = (half2_t*)(base + b); b += (size_t)6 * 4 * 8192 * 4;       // U(3) + W(3) packed
  half2_t* Hpk = (half2_t*)(base + b); b += (size_t)N_NODES * (HID / 2) * 4;
  float* Az  = (float*)(base + b); b += (size_t)N_NODES * HID * 4;
  float* Ar  = (float*)(base + b); b += (size_t)N_NODES * HID * 4;
  float* Ah  = (float*)(base + b); b += (size_t)N_NODES * HID * 4;
  float* H   = (float*)(base + b); b += (size_t)N_NODES * HID * 4;
  float* partial = (float*)(base + b); b += (size_t)64 * HID * 4;
  unsigned* counter = (unsigned*)(base + b); b += 256;

  prep_kernel<<<PK_BLKS + PO_BLKS + TR_BLKS, 256, 0, stream>>>(E, ETh, Uz, Ur, Uh, Wz, Wr, Wh,
                                                               Upk, (unsigned*)Hpk, counter);
  gather_gemv_kernel<<<N_NODES / 4, 256, 0, stream>>>(tree, (const half2_t*)ETh, Upk,
                                                      Az, Ar, Ah, H, Hpk);
  rnn_kernel<<<RNN_BLOCKS, 512, 0, stream>>>(Az, Ar, Ah, Upk, bz, br, bh, edge, H, (unsigned*)Hpk);
  leaffinal_kernel<<<64, HID, 0, stream>>>(H, leaf, Wout, bout, y, partial, counter, out);
}

// Round 11
// 511.194 us; speedup vs baseline: 1.2123x; 1.0068x over previous
//
#include <hip/hip_runtime.h>
#include <math.h>

#define N_NODES 4096
#define WORDS   64
#define HID     256
#define VOCAB   50257
#define NCLASS  4
#define N_LEAF  2048
#define RNN_BLOCKS 256     // 1 block/CU -> all resident, spin-wait safe
#define POISON 0x7FFF7FFFu // half2 (NaN,NaN); finite packed rows never match
#define TC_BX   786        // ceil(VOCAB/64) col-blocks for 64x64 transpose tiles
#define TR_BLKS (TC_BX * 4)            // 3144 transpose role blocks
#define PK_BLKS 96         // pack role blocks (LDS-free)
#define PO_BLKS 32         // poison role blocks (LDS-free)

typedef _Float16 half2_t __attribute__((ext_vector_type(2)));
typedef _Float16 half4_t __attribute__((ext_vector_type(4)));
typedef float    f4u     __attribute__((ext_vector_type(4), aligned(4)));  // 4B-aligned float4

__device__ __forceinline__ float dot2f(half2_t a, half2_t b, float c) {
#if __has_builtin(__builtin_amdgcn_fdot2)
  return __builtin_amdgcn_fdot2(a, b, c, false);   // v_dot2_f32_f16
#else
  return c + (float)a.x * (float)b.x + (float)a.y * (float)b.y;
#endif
}

__device__ __forceinline__ half2_t f2h2(float f) {
  union { float f; half2_t h; } u; u.f = f; return u.h;
}

__device__ __forceinline__ float fast_rcp(float x) { return __builtin_amdgcn_rcpf(x); }
__device__ __forceinline__ float fast_sigmoid(float x) {        // rcp-based, no IEEE div seq
  return fast_rcp(1.f + __expf(-x));
}
__device__ __forceinline__ float fast_tanh(float x) {           // 1 - 2/(e^{2x}+1); saturates to +-1
  return 1.f - 2.f * fast_rcp(1.f + __expf(2.f * x));
}
__device__ __forceinline__ half2_t pkrtz(float a, float b) {    // single v_cvt_pkrtz_f16_f32
#if __has_builtin(__builtin_amdgcn_cvt_pkrtz)
  return __builtin_bit_cast(half2_t, __builtin_amdgcn_cvt_pkrtz(a, b));
#else
  half2_t v; v.x = (_Float16)a; v.y = (_Float16)b; return v;
#endif
}

// ---------------------------------------------------------------- prep: pack | poison | transpose (one grid)
// R21: transpose role rewritten for instruction width (G13): 64x64 tiles (4x fewer blocks),
// float4 E reads, half4 8B/lane ETh writes (full 512B/wave lines vs 2B/lane scalar). LDS
// tile [64][68] pad -> 16B-aligned float4 readback, 2-way (free) banks. Pack/poison roles
// byte-identical to R20 (LDS-free). Max LDS 17.4KB -> 8 blocks/CU retained.
__global__ void __launch_bounds__(256) prep_kernel(
    const float* __restrict__ E, _Float16* __restrict__ ETh,
    const float* __restrict__ Uz, const float* __restrict__ Ur, const float* __restrict__ Uh,
    const float* __restrict__ Wz, const float* __restrict__ Wr, const float* __restrict__ Wh,
    half2_t* __restrict__ Upk, unsigned* __restrict__ HpkU, unsigned* __restrict__ counter) {
  __shared__ float tile[64][68];             // transpose role only (17.4 KB)
  const int t = threadIdx.x;
  int bb = blockIdx.x;

  if (bb < PK_BLKS) {
    // ---- pack role (LDS-free): m = bb>>4, kpg = bb&15; thread t = h
    const int m = bb >> 4, kpg = bb & 15;
    const float* U = m == 0 ? Uz : (m == 1 ? Ur : (m == 2 ? Uh : (m == 3 ? Wz : (m == 4 ? Wr : Wh))));
    const float* src = U + (size_t)t * 256 + kpg * 16;   // 64B-aligned, one line per thread
    float4 f0 = *(const float4*)(src + 0);
    float4 f1 = *(const float4*)(src + 4);
    float4 f2 = *(const float4*)(src + 8);
    float4 f3 = *(const float4*)(src + 12);
    half2_t* dst = Upk + (size_t)m * 32768 + (size_t)(kpg * 8) * 256 + t;
    half2_t v;
    v.x = (_Float16)f0.x; v.y = (_Float16)f0.y; dst[0 * 256] = v;
    v.x = (_Float16)f0.z; v.y = (_Float16)f0.w; dst[1 * 256] = v;
    v.x = (_Float16)f1.x; v.y = (_Float16)f1.y; dst[2 * 256] = v;
    v.x = (_Float16)f1.z; v.y = (_Float16)f1.w; dst[3 * 256] = v;
    v.x = (_Float16)f2.x; v.y = (_Float16)f2.y; dst[4 * 256] = v;
    v.x = (_Float16)f2.z; v.y = (_Float16)f2.w; dst[5 * 256] = v;
    v.x = (_Float16)f3.x; v.y = (_Float16)f3.y; dst[6 * 256] = v;
    v.x = (_Float16)f3.z; v.y = (_Float16)f3.w; dst[7 * 256] = v;
    return;
  }
  bb -= PK_BLKS;

  if (bb < PO_BLKS) {
    // ---- poison role (LDS-free): 32 blocks x 16384 words cover N_NODES*(HID/2)
    if (bb == 0 && t == 0) *counter = 0u;    // leaffinal completion counter (re-run safe)
    const int base = bb * 16384 + t;
#pragma unroll
    for (int k = 0; k < 64; ++k) HpkU[base + k * 256] = POISON;
    return;
  }
  bb -= PO_BLKS;

  // ---- transpose role: E (HID,VOCAB) f32 -> ETh (VOCAB,HID) f16; 64x64 tile
  {
    const int bx = bb % TC_BX, by = bb / TC_BX;
    const int c0 = bx * 64, r0 = by * 64;
    const int tlo = t & 15, thi = t >> 4;    // tlo: col-quad / row-quad; thi: row / col
#pragma unroll
    for (int j = 0; j < 4; ++j) {
      const int r  = r0 + thi + j * 16;      // global row, 0..255 (always valid)
      const int cc = c0 + tlo * 4;           // global col quad base
      const int tr = thi + j * 16;           // row within tile
      if (cc + 3 < VOCAB) {
        f4u v = *(const f4u*)(E + (size_t)r * VOCAB + cc);
        tile[tlo * 4 + 0][tr] = v.x;
        tile[tlo * 4 + 1][tr] = v.y;
        tile[tlo * 4 + 2][tr] = v.z;
        tile[tlo * 4 + 3][tr] = v.w;
      } else {
#pragma unroll
        for (int k = 0; k < 4; ++k)
          tile[tlo * 4 + k][tr] = (cc + k < VOCAB) ? E[(size_t)r * VOCAB + cc + k] : 0.f;
      }
    }
    __syncthreads();
#pragma unroll
    for (int jj = 0; jj < 4; ++jj) {
      const int c = c0 + jj * 16 + thi;      // global col
      if (c < VOCAB) {
        float4 f = *(const float4*)&tile[jj * 16 + thi][tlo * 4];   // 16B-aligned (68-pad)
        half4_t hv;
        hv.x = (_Float16)f.x; hv.y = (_Float16)f.y;   // RNE casts (match old transpose)
        hv.z = (_Float16)f.z; hv.w = (_Float16)f.w;
        *(half4_t*)(ETh + (size_t)c * HID + r0 + tlo * 4) = hv;     // 8B/lane, full lines
      }
    }
  }
}

// ---------------------------------------------------------------- fused gather + 3-gate GEMV
// R21: gather phase rewritten for load width (G13): float4 ETh reads (16B/lane, 4x fewer
// VMEM instrs), 8 words/thread, 8-way LDS reduce. ps2 layout [pair][g][quad] -> 2-way
// (free) banks on the store side. GEMV phase, Xh layout, node-0 seeding, f32 accumulation
// and RNE casts preserved from R15/R20 (proven 1024-block geometry).
__global__ void __launch_bounds__(256) gather_gemv_kernel(
    const int* __restrict__ tree, const half2_t* __restrict__ ETh2,
    const half2_t* __restrict__ Upk,
    float* __restrict__ Az, float* __restrict__ Ar, float* __restrict__ Ah,
    float* __restrict__ H, half2_t* __restrict__ Hpk) {
  const int t  = threadIdx.x;
  const int i0 = blockIdx.x * 4;
  __shared__ int     vsf[4 * WORDS];       // 4 nodes' word ids (contiguous in tree)
  __shared__ float2  ps2[4][8][32];        // gather partials [pair][g][quad] (8 KB)
  __shared__ half2_t Xh[4][HID / 2];       // 4 nodes' X rows, f16 pairs

  vsf[t] = tree[(size_t)i0 * WORDS + t];   // 4*64 = 256 words, coalesced
  __syncthreads();

  const int q = t & 31;                    // half2 col-quad (cols 4q..4q+3)
  const int g = t >> 5;                    // word octet (words 8g..8g+7)
#pragma unroll
  for (int n = 0; n < 4; ++n) {
    float a0x = 0.f, a0y = 0.f, a1x = 0.f, a1y = 0.f;
    float a2x = 0.f, a2y = 0.f, a3x = 0.f, a3y = 0.f;
    const int base = n * WORDS + g * 8;
#pragma unroll
    for (int w = 0; w < 8; ++w) {
      const float4* rowf = (const float4*)(ETh2 + (size_t)vsf[base + w] * (HID / 2));
      float4 ld = rowf[q];                 // 16B load; rows 512B-aligned
      half2_t h0 = __builtin_bit_cast(half2_t, ld.x);
      half2_t h1 = __builtin_bit_cast(half2_t, ld.y);
      half2_t h2 = __builtin_bit_cast(half2_t, ld.z);
      half2_t h3 = __builtin_bit_cast(half2_t, ld.w);
      a0x += (float)h0.x; a0y += (float)h0.y;
      a1x += (float)h1.x; a1y += (float)h1.y;
      a2x += (float)h2.x; a2y += (float)h2.y;
      a3x += (float)h3.x; a3y += (float)h3.y;
    }
    ps2[0][g][q].x = a0x; ps2[0][g][q].y = a0y;
    ps2[1][g][q].x = a1x; ps2[1][g][q].y = a1y;
    ps2[2][g][q].x = a2x; ps2[2][g][q].y = a2y;
    ps2[3][g][q].x = a3x; ps2[3][g][q].y = a3y;
    __syncthreads();
    if (t < 128) {                         // col c = t: quad q2 = c>>2, pair p = c&3
      const int q2 = t >> 2, p = t & 3;
      float xx = ((ps2[p][0][q2].x + ps2[p][1][q2].x) + (ps2[p][2][q2].x + ps2[p][3][q2].x))
               + ((ps2[p][4][q2].x + ps2[p][5][q2].x) + (ps2[p][6][q2].x + ps2[p][7][q2].x));
      float yy = ((ps2[p][0][q2].y + ps2[p][1][q2].y) + (ps2[p][2][q2].y + ps2[p][3][q2].y))
               + ((ps2[p][4][q2].y + ps2[p][5][q2].y) + (ps2[p][6][q2].y + ps2[p][7][q2].y));
      half2_t hv; hv.x = (_Float16)xx; hv.y = (_Float16)yy;   // RNE casts (match old gather)
      Xh[n][t] = hv;
      if (i0 + n == 0) {                   // node 0: seed fp32 H row + packed Hpk row
        float2 v2; v2.x = xx; v2.y = yy;
        ((float2*)H)[t] = v2;
        Hpk[t] = hv;
      }
    }
    __syncthreads();                       // ps2 reusable; Xh[n] visible to all
  }

  // ---- GEMV: 3 gates x 4 nodes, output neuron = t (unchanged from R15/R20)
  float acc[3][4];
#pragma unroll
  for (int m = 0; m < 3; ++m)
#pragma unroll
    for (int n = 0; n < 4; ++n) acc[m][n] = 0.f;

  const half2_t* wb = Upk + (size_t)12 * 8192 + t;   // m=3 (Wz) base, +32768 per gate
#pragma unroll 8
  for (int kp = 0; kp < 128; ++kp) {
    half2_t w0 = wb[kp * 256];
    half2_t w1 = wb[kp * 256 + 32768];
    half2_t w2 = wb[kp * 256 + 65536];
    half2_t x0 = Xh[0][kp], x1 = Xh[1][kp], x2 = Xh[2][kp], x3 = Xh[3][kp];  // LDS broadcast
    acc[0][0] = dot2f(w0, x0, acc[0][0]); acc[0][1] = dot2f(w0, x1, acc[0][1]);
    acc[0][2] = dot2f(w0, x2, acc[0][2]); acc[0][3] = dot2f(w0, x3, acc[0][3]);
    acc[1][0] = dot2f(w1, x0, acc[1][0]); acc[1][1] = dot2f(w1, x1, acc[1][1]);
    acc[1][2] = dot2f(w1, x2, acc[1][2]); acc[1][3] = dot2f(w1, x3, acc[1][3]);
    acc[2][0] = dot2f(w2, x0, acc[2][0]); acc[2][1] = dot2f(w2, x1, acc[2][1]);
    acc[2][2] = dot2f(w2, x2, acc[2][2]); acc[2][3] = dot2f(w2, x3, acc[2][3]);
  }
#pragma unroll
  for (int n = 0; n < 4; ++n) {
    Az[(size_t)(i0 + n) * HID + t] = acc[0][n];
    Ar[(size_t)(i0 + n) * HID + t] = acc[1][n];
    Ah[(size_t)(i0 + n) * HID + t] = acc[2][n];
  }
}

// ---------------------------------------------------------------- persistent wavefront GRU scan (block-cyclic)
// R21 = R15's scan BYTE-IDENTICAL. It sits at its dependency roofline: 334us = ~802K cy ~=
// D (~1000 critical-path steps) x ~800 cy, where ~768 cy is the invariant per-node VALU
// issue (1536 wave-dot2 / 4 SIMD x 2cy) -- handoff overhead is already ~0, which is why
// all six scan redesigns (R1/R12/R14/R16/R17/R18) regressed.
// All U loops FULLY unrolled (R6 lesson: partial unroll -> alloca -> LDS/scratch catastrophe).
__global__ void
__attribute__((amdgpu_flat_work_group_size(512, 512), amdgpu_waves_per_eu(2, 2)))
rnn_kernel(
    const float* __restrict__ Az, const float* __restrict__ Ar, const float* __restrict__ Ah,
    const half2_t* __restrict__ Upk,
    const float* __restrict__ bz, const float* __restrict__ br, const float* __restrict__ bh,
    const int* __restrict__ edge, float* __restrict__ H, unsigned* HpkU) {
  const int tid = threadIdx.x;
  const int h   = tid & (HID - 1);
  const int ks  = tid >> 8;            // 0..1
  __shared__ half2_t php[HID / 2];
  __shared__ half2_t rhp[HID / 2];
  __shared__ float   part[2 * HID];

  // one-time U load (full unroll -> SSA -> register file)
  half2_t um[128];   // Uz (ks0) or Ur (ks1), full K
  half2_t uhh[64];   // Uh, k-slice [ks*128, ks*128+128)
  {
    const half2_t* mb = Upk + (size_t)(ks ? 4 : 0) * 8192 + h;
#pragma unroll
    for (int j = 0; j < 128; ++j)
      um[j] = mb[(j >> 5) * 8192 + (j & 31) * 256];
    const half2_t* hb = Upk + (size_t)(8 + 2 * ks) * 8192 + h;
#pragma unroll
    for (int j = 0; j < 64; ++j)
      uhh[j] = hb[(j >> 5) * 8192 + (j & 31) * 256];
  }
  const float b1  = ks ? br[h] : bz[h];
  const float bhv = ks ? 0.f : bh[h];

  const int istart = blockIdx.x == 0 ? RNN_BLOCKS : blockIdx.x;  // node 0 pre-seeded by gather
  for (int i = istart; i < N_NODES; i += RNN_BLOCKS) {
    const int p = edge[2 * i];   // parent, p < i
    // A-row loads issued before the poll; they complete while waiting
    const float a1 = ks ? Ar[(size_t)i * HID + h] : Az[(size_t)i * HID + h];
    const float a2 = ks ? 0.f : Ah[(size_t)i * HID + h];

    if (tid < HID / 2) {
      unsigned v = __hip_atomic_load(&HpkU[(size_t)p * (HID / 2) + tid],
                                     __ATOMIC_RELAXED, __HIP_MEMORY_SCOPE_AGENT);
      long spin = 0;
      while (v == POISON) {
        if (++spin > (1L << 22)) break;   // escape hatch (should never trigger)
        v = __hip_atomic_load(&HpkU[(size_t)p * (HID / 2) + tid],
                              __ATOMIC_RELAXED, __HIP_MEMORY_SCOPE_AGENT);
      }
      php[tid] = __builtin_bit_cast(half2_t, v);
    }
    __syncthreads();   // B0: packed parent row resident in LDS

    // parent element for this h, decoded from fp16 row
    half2_t ph2 = php[h >> 1];
    const float phv = (float)((h & 1) ? ph2.y : ph2.x);

    // phase 1: full-K dot of Uz (ks0) / Ur (ks1) against packed parent row
    float ac0 = a1 + b1, ac1 = 0.f, ac2 = 0.f, ac3 = 0.f;
    {
      const float4* phq = (const float4*)php;
#pragma unroll
      for (int q = 0; q < 32; ++q) {
        float4 blk = phq[q];
        ac0 = dot2f(um[4 * q + 0], f2h2(blk.x), ac0);
        ac1 = dot2f(um[4 * q + 1], f2h2(blk.y), ac1);
        ac2 = dot2f(um[4 * q + 2], f2h2(blk.z), ac2);
        ac3 = dot2f(um[4 * q + 3], f2h2(blk.w), ac3);
      }
    }
    const float g = fast_sigmoid((ac0 + ac1) + (ac2 + ac3));
    if (ks) {                    // r gate -> packed r*ph
      float rh = g * phv;
      float nb = __shfl_xor(rh, 1, 64);
      if ((h & 1) == 0) rhp[h >> 1] = pkrtz(rh, nb);
    }
    __syncthreads();   // B1

    // phase 2: Uh partial dots over this thread's k-slice
    float c0 = 0.f, c1 = 0.f;
    {
      const float4* rq = (const float4*)(rhp + ks * 64);
#pragma unroll
      for (int q = 0; q < 16; ++q) {
        float4 blk = rq[q];
        c0 = dot2f(uhh[4 * q + 0], f2h2(blk.x), c0);
        c1 = dot2f(uhh[4 * q + 1], f2h2(blk.y), c1);
        c0 = dot2f(uhh[4 * q + 2], f2h2(blk.z), c0);
        c1 = dot2f(uhh[4 * q + 3], f2h2(blk.w), c1);
      }
    }
    part[ks * HID + h] = c0 + c1;
    __syncthreads();   // B2

    if (ks == 0) {
      float ca = a2 + bhv + part[h] + part[HID + h];
      float c  = fast_tanh(ca);
      float hn = fmaf(g, phv, (1.f - g) * c);
      float nb = __shfl_xor(hn, 1, 64);   // DPP xor-1
      if ((h & 1) == 0) {                 // handoff store FIRST (children poll this)
        __hip_atomic_store(&HpkU[(size_t)i * (HID / 2) + (h >> 1)],
                           __builtin_bit_cast(unsigned, pkrtz(hn, nb)),
                           __ATOMIC_RELAXED, __HIP_MEMORY_SCOPE_AGENT);
      }
      H[(size_t)i * HID + h] = hn;        // fp32 row for leafmax (off critical path)
    }
    // no publish barrier, no waitcnt, no flag: the row stores are the signal
  }
}

// ---------------------------------------------------------------- leafmax + final, fused (last-block pattern)
// R19 (kept): 64 blocks compute partial leaf-maxes; the last block (device-scope counter)
// runs the final W_out/softmax/loss. Counter zeroed by prep each run (re-run safe).
__global__ void leaffinal_kernel(const float* __restrict__ H, const int* __restrict__ leafs,
                                 const float* __restrict__ W_out, const float* __restrict__ b_out,
                                 const float* __restrict__ y,
                                 float* __restrict__ partial, unsigned* __restrict__ counter,
                                 float* __restrict__ out) {
  const int b = blockIdx.x;
  const int h = threadIdx.x;
  float m = -INFINITY;
#pragma unroll 4
  for (int j = 0; j < N_LEAF / 64; ++j) {
    int node = leafs[b * (N_LEAF / 64) + j];
    m = fmaxf(m, H[(size_t)node * HID + h]);
  }
  partial[b * HID + h] = m;
  __threadfence();                       // release partial stores (device scope)
  __syncthreads();
  __shared__ int last;
  if (h == 0) last = (atomicAdd(counter, 1u) == 63u);
  __syncthreads();
  if (!last) return;
  __threadfence();                       // acquire other blocks' partials

  float mm = -INFINITY;
#pragma unroll 8
  for (int bb = 0; bb < 64; ++bb) mm = fmaxf(mm, partial[bb * HID + h]);
  __shared__ float fs[HID];
  __shared__ float red[HID];
  __shared__ float logit[NCLASS];
  fs[h] = mm;
  __syncthreads();
  for (int c = 0; c < NCLASS; ++c) {
    red[h] = W_out[c * HID + h] * fs[h];
    __syncthreads();
    for (int s = HID / 2; s > 0; s >>= 1) {
      if (h < s) red[h] += red[h + s];
      __syncthreads();
    }
    if (h == 0) logit[c] = red[0] + b_out[c];
    __syncthreads();
  }
  if (h == 0) {
    float mx = logit[0];
    for (int c = 1; c < NCLASS; ++c) mx = fmaxf(mx, logit[c]);
    float e[NCLASS], s = 0.f;
    for (int c = 0; c < NCLASS; ++c) { e[c] = expf(logit[c] - mx); s += e[c]; }
    float loss = 0.f;
    for (int c = 0; c < NCLASS; ++c) {
      float p = e[c] / s;
      out[c] = p;
      float d = y[c] - p;
      loss += d * d;
    }
    out[NCLASS] = loss;
  }
}

// ---------------------------------------------------------------- launch
extern "C" void kernel_launch(void* const* d_in, const int* in_sizes, int n_in,
                              void* d_out, int out_size, void* d_ws, size_t ws_size,
                              hipStream_t stream) {
  const int*   tree = (const int*)d_in[0];
  const int*   edge = (const int*)d_in[1];
  const int*   leaf = (const int*)d_in[2];
  const float* y    = (const float*)d_in[3];
  const float* E    = (const float*)d_in[4];
  const float* Wz   = (const float*)d_in[5];
  const float* Uz   = (const float*)d_in[6];
  const float* bz   = (const float*)d_in[7];
  const float* Wr   = (const float*)d_in[8];
  const float* Ur   = (const float*)d_in[9];
  const float* br   = (const float*)d_in[10];
  const float* Wh   = (const float*)d_in[11];
  const float* Uh   = (const float*)d_in[12];
  const float* bh   = (const float*)d_in[13];
  const float* Wout = (const float*)d_in[14];
  const float* bout = (const float*)d_in[15];
  float* out = (float*)d_out;

  char* base = (char*)d_ws;
  size_t b = 0;
  _Float16* ETh = (_Float16*)(base + b); b += (size_t)VOCAB * HID * 2;      // 25.7 MB
  b = (b + 255) & ~(size_t)255;
  half2_t* Upk = (half2_t*)(base + b); b += (size_t)6 * 4 * 8192 * 4;       // U(3) + W(3) packed
  half2_t* Hpk = (half2_t*)(base + b); b += (size_t)N_NODES * (HID / 2) * 4;
  float* Az  = (float*)(base + b); b += (size_t)N_NODES * HID * 4;
  float* Ar  = (float*)(base + b); b += (size_t)N_NODES * HID * 4;
  float* Ah  = (float*)(base + b); b += (size_t)N_NODES * HID * 4;
  float* H   = (float*)(base + b); b += (size_t)N_NODES * HID * 4;
  float* partial = (float*)(base + b); b += (size_t)64 * HID * 4;
  unsigned* counter = (unsigned*)(base + b); b += 256;

  prep_kernel<<<PK_BLKS + PO_BLKS + TR_BLKS, 256, 0, stream>>>(E, ETh, Uz, Ur, Uh, Wz, Wr, Wh,
                                                               Upk, (unsigned*)Hpk, counter);
  gather_gemv_kernel<<<N_NODES / 4, 256, 0, stream>>>(tree, (const half2_t*)ETh, Upk,
                                                      Az, Ar, Ah, H, Hpk);
  rnn_kernel<<<RNN_BLOCKS, 512, 0, stream>>>(Az, Ar, Ah, Upk, bz, br, bh, edge, H, (unsigned*)Hpk);
  leaffinal_kernel<<<64, HID, 0, stream>>>(H, leaf, Wout, bout, y, partial, counter, out);
}